// Round 5
// baseline (138.168 us; speedup 1.0000x reference)
//
#include <hip/hip_runtime.h>
#include <math.h>

#define BB 32
#define TT 1024
#define JJ 128
#define DD 256

typedef unsigned short u16;
typedef short s16x8 __attribute__((ext_vector_type(8)));
typedef float f32x4 __attribute__((ext_vector_type(4)));

#define MFMA_BF16(a, b, c) __builtin_amdgcn_mfma_f32_16x16x32_bf16((a), (b), (c), 0, 0, 0)

__device__ inline u16 f2bf(float f) {
    unsigned int u = __float_as_uint(f);
    u += 0x7FFFu + ((u >> 16) & 1u);
    return (u16)(u >> 16);
}
__device__ inline float bf2f(u16 h) {
    return __uint_as_float(((unsigned int)h) << 16);
}

// ---------------------------------------------------------------------------
// K0a: per 64-t tile: ch[t] = C[t,:]·w_h ; CtT[b,d,t] = bf16(C[b,t,d])^T.
// One C read serves both. LDS transpose, stride 80 u16 (16B-aligned rows).
// ---------------------------------------------------------------------------
__global__ __launch_bounds__(256) void k_cprep(const float* __restrict__ C,
                                               const float* __restrict__ w,
                                               float* __restrict__ ch,
                                               u16* __restrict__ CtT) {
    const int b = blockIdx.y, t0 = blockIdx.x * 64;
    const int tid = threadIdx.x;
    __shared__ float sW[256];
    __shared__ __align__(16) u16 sTr[256 * 80];   // [d][t] stride 80
    sW[tid] = w[tid];
    __syncthreads();
    const int r = tid >> 2, s = tid & 3;          // row r (64), d-seg s (4x64)
    const float* cp = C + ((size_t)(b * TT + t0 + r)) * DD + s * 64;
    float dot = 0.f;
    #pragma unroll
    for (int q = 0; q < 16; q++) {
        float4 v = *(const float4*)(cp + q * 4);
        const float* wq = &sW[s * 64 + q * 4];
        dot += v.x * wq[0] + v.y * wq[1] + v.z * wq[2] + v.w * wq[3];
        int d = s * 64 + q * 4;
        sTr[(d + 0) * 80 + r] = f2bf(v.x);
        sTr[(d + 1) * 80 + r] = f2bf(v.y);
        sTr[(d + 2) * 80 + r] = f2bf(v.z);
        sTr[(d + 3) * 80 + r] = f2bf(v.w);
    }
    dot += __shfl_xor(dot, 1, 64);
    dot += __shfl_xor(dot, 2, 64);
    if (s == 0) ch[(size_t)b * TT + t0 + r] = dot;
    __syncthreads();
    // readback: one d-row per thread, 64 t contiguous
    const u16* srow = &sTr[tid * 80];
    u16* drow = &CtT[((size_t)b * DD + tid) * TT + t0];
    #pragma unroll
    for (int q = 0; q < 8; q++) *(uint4*)&drow[q * 8] = *(const uint4*)&srow[q * 8];
}

// ---------------------------------------------------------------------------
// K0b: per batch: qu[j] = Q[j,:]·w_u ; Qhi/Qlo[j,d] split bf16 ; Qt[d,j] bf16.
// One Q read serves all. LDS transpose stride 144 u16.
// ---------------------------------------------------------------------------
__global__ __launch_bounds__(256) void k_qprep(const float* __restrict__ Q,
                                               const float* __restrict__ w,
                                               float* __restrict__ qu,
                                               u16* __restrict__ Qhi,
                                               u16* __restrict__ Qlo,
                                               u16* __restrict__ Qt) {
    const int b = blockIdx.x;
    const int tid = threadIdx.x;
    __shared__ float sW[256];
    __shared__ __align__(16) u16 sTr[256 * 144];  // [d][j] stride 144
    sW[tid] = w[DD + tid];
    __syncthreads();
    const int j = tid >> 1, half = tid & 1;       // 128 j x 2 d-halves
    const float* qp = Q + ((size_t)b * JJ + j) * DD + half * 128;
    u16* hp = Qhi + ((size_t)b * JJ + j) * DD + half * 128;
    u16* lp = Qlo + ((size_t)b * JJ + j) * DD + half * 128;
    float dot = 0.f;
    #pragma unroll
    for (int q = 0; q < 32; q++) {
        float4 v = *(const float4*)(qp + q * 4);
        const float* wq = &sW[half * 128 + q * 4];
        dot += v.x * wq[0] + v.y * wq[1] + v.z * wq[2] + v.w * wq[3];
        ushort4 h, l;
        h.x = f2bf(v.x); l.x = f2bf(v.x - bf2f(h.x));
        h.y = f2bf(v.y); l.y = f2bf(v.y - bf2f(h.y));
        h.z = f2bf(v.z); l.z = f2bf(v.z - bf2f(h.z));
        h.w = f2bf(v.w); l.w = f2bf(v.w - bf2f(h.w));
        *(ushort4*)(hp + q * 4) = h;
        *(ushort4*)(lp + q * 4) = l;
        int d = half * 128 + q * 4;
        sTr[(d + 0) * 144 + j] = h.x;
        sTr[(d + 1) * 144 + j] = h.y;
        sTr[(d + 2) * 144 + j] = h.z;
        sTr[(d + 3) * 144 + j] = h.w;
    }
    dot += __shfl_xor(dot, 1, 64);
    if (half == 0) qu[b * JJ + j] = dot;
    __syncthreads();
    const u16* srow = &sTr[tid * 144];
    u16* drow = &Qt[((size_t)b * DD + tid) * JJ];
    #pragma unroll
    for (int q = 0; q < 16; q++) *(uint4*)&drow[q * 8] = *(const uint4*)&srow[q * 8];
}

// ---------------------------------------------------------------------------
// K2 (split-bf16 MFMA): S = ch + qu + (C*w_hu)·Q^T via hi/lo decomposition.
// Epilogue: row stats, column partials, X = exp(S - rowmax) bf16.
// ---------------------------------------------------------------------------
__global__ __launch_bounds__(256) void k_S(const float* __restrict__ C,
                                           const u16* __restrict__ Qhi,
                                           const u16* __restrict__ Qlo,
                                           const float* __restrict__ w,
                                           const float* __restrict__ ch,
                                           const float* __restrict__ qu,
                                           u16* __restrict__ Xg,
                                           float* __restrict__ rowmax,
                                           float* __restrict__ rowrcp,
                                           float* __restrict__ pm,
                                           float* __restrict__ ps) {
    const int b  = blockIdx.y;
    const int bx = blockIdx.x;
    const int t0 = bx * 64;
    const int tid = threadIdx.x;

    union SMem {
        struct { u16 Ah[64 * 72]; u16 Al[64 * 72]; u16 Bh[128 * 72]; u16 Bl[128 * 72]; } g;
        struct { float S[64 * 132]; float RM[64]; float PM2[256]; float PS2[256]; } e;
    };
    __shared__ __align__(16) SMem sm;
    __shared__ float sCH[64];
    __shared__ float sQU[128];

    if (tid < 64)  sCH[tid] = ch[(size_t)b * TT + t0 + tid];
    if (tid < 128) sQU[tid] = qu[b * JJ + tid];

    const float* whu = w + 2 * DD;
    const float* Cb  = C + ((size_t)b * TT + t0) * DD;

    const int lane = tid & 63, wv = tid >> 6;
    const int wm = wv >> 1, wn = wv & 1;
    const int lr = lane & 15, lg = lane >> 4;

    f32x4 zero4 = {0.f, 0.f, 0.f, 0.f};
    f32x4 acc[2][4];
    #pragma unroll
    for (int m = 0; m < 2; m++)
        #pragma unroll
        for (int n = 0; n < 4; n++) acc[m][n] = zero4;

    const int tA = tid >> 2, sA = (tid & 3) * 16;
    const int jB = tid >> 1, sB = (tid & 1) * 32;

    for (int kc = 0; kc < DD; kc += 64) {
        __syncthreads();
        {   // stage A: (C*w_hu)[64t][64k] -> hi/lo bf16
            const float* cp = Cb + (size_t)tA * DD + kc + sA;
            const float* wp = whu + kc + sA;
            float cc[16], ww[16];
            #pragma unroll
            for (int q = 0; q < 4; q++) {
                *(float4*)&cc[q * 4] = *(const float4*)(cp + q * 4);
                *(float4*)&ww[q * 4] = *(const float4*)(wp + q * 4);
            }
            u16 hi16[16], lo16[16];
            #pragma unroll
            for (int u = 0; u < 16; u++) {
                float v = cc[u] * ww[u];
                u16 h = f2bf(v);
                hi16[u] = h;
                lo16[u] = f2bf(v - bf2f(h));
            }
            int o = tA * 72 + sA;
            *(uint4*)&sm.g.Ah[o]     = *(uint4*)&hi16[0];
            *(uint4*)&sm.g.Ah[o + 8] = *(uint4*)&hi16[8];
            *(uint4*)&sm.g.Al[o]     = *(uint4*)&lo16[0];
            *(uint4*)&sm.g.Al[o + 8] = *(uint4*)&lo16[8];
        }
        {   // stage B: Qhi/Qlo[128j][64k] (pure copies)
            const uint4* qh = (const uint4*)&Qhi[((size_t)b * JJ + jB) * DD + kc + sB];
            const uint4* ql = (const uint4*)&Qlo[((size_t)b * JJ + jB) * DD + kc + sB];
            uint4* dh = (uint4*)&sm.g.Bh[jB * 72 + sB];
            uint4* dl = (uint4*)&sm.g.Bl[jB * 72 + sB];
            #pragma unroll
            for (int q = 0; q < 4; q++) { dh[q] = qh[q]; dl[q] = ql[q]; }
        }
        __syncthreads();
        #pragma unroll
        for (int ks = 0; ks < 2; ks++) {
            const int ko = ks * 32 + lg * 8;
            s16x8 ah[2], al[2], bh[4], bl[4];
            #pragma unroll
            for (int m = 0; m < 2; m++) {
                ah[m] = *(const s16x8*)&sm.g.Ah[(wm * 32 + m * 16 + lr) * 72 + ko];
                al[m] = *(const s16x8*)&sm.g.Al[(wm * 32 + m * 16 + lr) * 72 + ko];
            }
            #pragma unroll
            for (int n = 0; n < 4; n++) {
                bh[n] = *(const s16x8*)&sm.g.Bh[(wn * 64 + n * 16 + lr) * 72 + ko];
                bl[n] = *(const s16x8*)&sm.g.Bl[(wn * 64 + n * 16 + lr) * 72 + ko];
            }
            #pragma unroll
            for (int m = 0; m < 2; m++)
                #pragma unroll
                for (int n = 0; n < 4; n++) {
                    f32x4 t = acc[m][n];
                    t = MFMA_BF16(ah[m], bh[n], t);
                    t = MFMA_BF16(ah[m], bl[n], t);
                    t = MFMA_BF16(al[m], bh[n], t);
                    acc[m][n] = t;
                }
        }
    }

    // ---- epilogue ----
    __syncthreads();
    #pragma unroll
    for (int m = 0; m < 2; m++) {
        int row0 = wm * 32 + m * 16 + lg * 4;
        #pragma unroll
        for (int n = 0; n < 4; n++) {
            int col = wn * 64 + n * 16 + lr;
            float qv = sQU[col];
            #pragma unroll
            for (int reg = 0; reg < 4; reg++)
                sm.e.S[(row0 + reg) * 132 + col] = acc[m][n][reg] + sCH[row0 + reg] + qv;
        }
    }
    __syncthreads();
    {   // row stats: 4 threads per row
        int r = tid >> 2, s = tid & 3;
        float v[32];
        const float* Sr = &sm.e.S[r * 132 + s * 32];
        #pragma unroll
        for (int q = 0; q < 8; q++) *(float4*)&v[q * 4] = *(const float4*)&Sr[q * 4];
        float mx = v[0];
        #pragma unroll
        for (int u = 1; u < 32; u++) mx = fmaxf(mx, v[u]);
        mx = fmaxf(mx, __shfl_xor(mx, 1, 64));
        mx = fmaxf(mx, __shfl_xor(mx, 2, 64));
        float sum = 0.f;
        #pragma unroll
        for (int u = 0; u < 32; u++) sum += __expf(v[u] - mx);
        sum += __shfl_xor(sum, 1, 64);
        sum += __shfl_xor(sum, 2, 64);
        if (s == 0) {
            sm.e.RM[r] = mx;
            rowmax[(size_t)b * TT + t0 + r] = mx;
            rowrcp[(size_t)b * TT + t0 + r] = 1.0f / sum;
        }
    }
    {   // column partials (two t-halves per column)
        int j = tid & 127, h = tid >> 7;
        float cm = -1e30f;
        #pragma unroll
        for (int k = 0; k < 32; k++) cm = fmaxf(cm, sm.e.S[(h * 32 + k) * 132 + j]);
        float cs = 0.f;
        #pragma unroll
        for (int k = 0; k < 32; k++) cs += __expf(sm.e.S[(h * 32 + k) * 132 + j] - cm);
        sm.e.PM2[h * 128 + j] = cm;
        sm.e.PS2[h * 128 + j] = cs;
    }
    __syncthreads();
    if (tid < 128) {
        float m0 = sm.e.PM2[tid], m1 = sm.e.PM2[128 + tid];
        float M = fmaxf(m0, m1);
        float S2 = sm.e.PS2[tid] * __expf(m0 - M) + sm.e.PS2[128 + tid] * __expf(m1 - M);
        pm[((size_t)b * 16 + bx) * JJ + tid] = M;
        ps[((size_t)b * 16 + bx) * JJ + tid] = S2;
    }
    // X = exp(S - rowmax) bf16
    #pragma unroll
    for (int i = 0; i < 4; i++) {
        int c = tid + 256 * i;
        int row = c >> 4, j0 = (c & 15) * 8;
        float rm = sm.e.RM[row];
        float vv[8];
        *(float4*)&vv[0] = *(const float4*)&sm.e.S[row * 132 + j0];
        *(float4*)&vv[4] = *(const float4*)&sm.e.S[row * 132 + j0 + 4];
        u16 xp[8];
        #pragma unroll
        for (int u = 0; u < 8; u++) xp[u] = f2bf(__expf(vv[u] - rm));
        *(uint4*)&Xg[((size_t)b * TT + t0 + row) * JJ + j0] = *(uint4*)&xp[0];
    }
}

// ---------------------------------------------------------------------------
// K3: per-batch reduce: K_b = max_t rowmax; er[t] = exp(rowmax - K_b);
// ec[j] = exp(K_b - colmax)/colsum.
// ---------------------------------------------------------------------------
__global__ __launch_bounds__(256) void k_colred(const float* __restrict__ pm,
                                                const float* __restrict__ ps,
                                                const float* __restrict__ rowmax,
                                                float* __restrict__ er,
                                                float* __restrict__ ec) {
    const int b = blockIdx.x;
    const int tid = threadIdx.x;
    __shared__ float sW[4];
    float m = -1e30f;
    #pragma unroll
    for (int k = 0; k < 4; k++) m = fmaxf(m, rowmax[(size_t)b * TT + tid + 256 * k]);
    #pragma unroll
    for (int off = 32; off; off >>= 1) m = fmaxf(m, __shfl_xor(m, off, 64));
    if ((tid & 63) == 0) sW[tid >> 6] = m;
    __syncthreads();
    const float K = fmaxf(fmaxf(sW[0], sW[1]), fmaxf(sW[2], sW[3]));
    #pragma unroll
    for (int k = 0; k < 4; k++) {
        int i = tid + 256 * k;
        er[(size_t)b * TT + i] = __expf(rowmax[(size_t)b * TT + i] - K);
    }
    if (tid < JJ) {
        float cm = -1e30f;
        #pragma unroll
        for (int tb = 0; tb < 16; tb++) cm = fmaxf(cm, pm[((size_t)b * 16 + tb) * JJ + tid]);
        float cs = 0.f;
        #pragma unroll
        for (int tb = 0; tb < 16; tb++)
            cs += ps[((size_t)b * 16 + tb) * JJ + tid] * __expf(pm[((size_t)b * 16 + tb) * JJ + tid] - cm);
        ec[b * JJ + tid] = __expf(K - cm) / cs;
    }
}

// ---------------------------------------------------------------------------
// K4 (MFMA): Tt[b,d,j] = sum_t G[t,j]*C[t,d], G = X*er[t]*ec[j].
// d-split 2; id swizzle keeps both halves of a batch on one XCD
// (X L2-reuse). C^T staged from CtT by pure uint4 copies.
// ---------------------------------------------------------------------------
__global__ __launch_bounds__(256) void k_tmp(const u16* __restrict__ Xg,
                                             const u16* __restrict__ CtT,
                                             const float* __restrict__ er,
                                             const float* __restrict__ ec,
                                             u16* __restrict__ Tt) {
    const int id = blockIdx.x;
    const int b = id & 31, dh = id >> 5;          // id = dh*32 + b
    const int d0 = dh * 128;
    const int tid = threadIdx.x;
    __shared__ __align__(16) u16 sG[128 * 72];    // [j][t] stride 72
    __shared__ __align__(16) u16 sCt[128 * 72];   // [d][t] stride 72
    __shared__ float sEC[128];
    if (tid < 128) sEC[tid] = ec[b * JJ + tid];
    const int lane = tid & 63, wv = tid >> 6;
    const int lr = lane & 15, lg = lane >> 4;
    f32x4 zero4 = {0.f, 0.f, 0.f, 0.f};
    f32x4 acc[2][8];
    #pragma unroll
    for (int m = 0; m < 2; m++)
        #pragma unroll
        for (int n = 0; n < 8; n++) acc[m][n] = zero4;

    for (int tt = 0; tt < TT; tt += 64) {
        __syncthreads();
        // stage G^T = X * er * ec (bf16), [j][t]
        #pragma unroll
        for (int i = 0; i < 4; i++) {
            int c = tid + 256 * i;
            int trow = c >> 4, j0 = (c & 15) * 8;
            float e = er[(size_t)b * TT + tt + trow];
            uint4 xv = *(const uint4*)&Xg[((size_t)b * TT + tt + trow) * JJ + j0];
            const u16* xp = (const u16*)&xv;
            #pragma unroll
            for (int u = 0; u < 8; u++)
                sG[(j0 + u) * 72 + trow] = f2bf(bf2f(xp[u]) * e * sEC[j0 + u]);
        }
        // stage C^T: pure copies from CtT
        #pragma unroll
        for (int i = 0; i < 4; i++) {
            int c = tid + 256 * i;
            int drow = c >> 3, to8 = (c & 7) * 8;
            *(uint4*)&sCt[drow * 72 + to8] =
                *(const uint4*)&CtT[((size_t)b * DD + d0 + drow) * TT + tt + to8];
        }
        __syncthreads();
        #pragma unroll
        for (int ks = 0; ks < 2; ks++) {
            int ko = ks * 32 + lg * 8;
            s16x8 a0 = *(const s16x8*)&sG[(wv * 32 + lr) * 72 + ko];
            s16x8 a1 = *(const s16x8*)&sG[(wv * 32 + 16 + lr) * 72 + ko];
            #pragma unroll
            for (int n = 0; n < 8; n++) {
                s16x8 bn = *(const s16x8*)&sCt[(n * 16 + lr) * 72 + ko];
                acc[0][n] = MFMA_BF16(a0, bn, acc[0][n]);
                acc[1][n] = MFMA_BF16(a1, bn, acc[1][n]);
            }
        }
    }
    #pragma unroll
    for (int mr = 0; mr < 2; mr++)
        #pragma unroll
        for (int n = 0; n < 8; n++)
            #pragma unroll
            for (int reg = 0; reg < 4; reg++) {
                int j = wv * 32 + mr * 16 + lg * 4 + reg;
                int d = d0 + n * 16 + lr;
                Tt[((size_t)b * DD + d) * JJ + j] = f2bf(acc[mr][n][reg]);
            }
}

// ---------------------------------------------------------------------------
// K5 (MFMA): A = (X·rowrcp)·Q, Bm = (X·rowrcp)·tmp; out = [C, A, C*A, C*Bm].
// 1-D grid, id = b*64 + dc*16 + tc so the 4 dc-blocks sharing an X-tile
// land on the same XCD (id%8 = tc%8). C values come from CtT (bf16).
// ---------------------------------------------------------------------------
__global__ __launch_bounds__(256) void k_out(const u16* __restrict__ Xg,
                                             const u16* __restrict__ Qt,
                                             const u16* __restrict__ Tt,
                                             const u16* __restrict__ CtT,
                                             const float* __restrict__ rowrcp,
                                             float* __restrict__ out) {
    const int id = blockIdx.x;
    const int b = id >> 6, dc = (id >> 4) & 3, tc = id & 15;
    const int t0 = tc * 64, d0 = dc * 64;
    const int tid = threadIdx.x;
    __shared__ __align__(16) u16 sX[64 * 136];
    __shared__ __align__(16) u16 sQ[64 * 136];
    __shared__ __align__(16) u16 sT[64 * 136];
    const size_t xbase = ((size_t)b * TT + t0) * JJ;
    const size_t qbase = ((size_t)b * DD + d0) * JJ;
    #pragma unroll
    for (int i = 0; i < 4; i++) {
        int c = tid + 256 * i;
        int row = c >> 4, col = (c & 15) * 8;
        int lo = row * 136 + col;
        *(uint4*)&sX[lo] = *(const uint4*)&Xg[xbase + (size_t)row * JJ + col];
        *(uint4*)&sQ[lo] = *(const uint4*)&Qt[qbase + (size_t)row * JJ + col];
        *(uint4*)&sT[lo] = *(const uint4*)&Tt[qbase + (size_t)row * JJ + col];
    }
    __syncthreads();
    const int lane = tid & 63, wv = tid >> 6;
    const int wm = wv >> 1, wn = wv & 1;
    const int lr = lane & 15, lg = lane >> 4;
    f32x4 zero4 = {0.f, 0.f, 0.f, 0.f};
    f32x4 accA[2][2], accB[2][2];
    #pragma unroll
    for (int mr = 0; mr < 2; mr++)
        #pragma unroll
        for (int nr = 0; nr < 2; nr++) { accA[mr][nr] = zero4; accB[mr][nr] = zero4; }

    #pragma unroll
    for (int ks = 0; ks < 4; ks++) {
        int kc = ks * 32 + lg * 8;
        s16x8 a0 = *(const s16x8*)&sX[(wm * 32 + lr) * 136 + kc];
        s16x8 a1 = *(const s16x8*)&sX[(wm * 32 + 16 + lr) * 136 + kc];
        s16x8 q0 = *(const s16x8*)&sQ[(wn * 32 + lr) * 136 + kc];
        s16x8 q1 = *(const s16x8*)&sQ[(wn * 32 + 16 + lr) * 136 + kc];
        s16x8 u0 = *(const s16x8*)&sT[(wn * 32 + lr) * 136 + kc];
        s16x8 u1 = *(const s16x8*)&sT[(wn * 32 + 16 + lr) * 136 + kc];
        accA[0][0] = MFMA_BF16(a0, q0, accA[0][0]);
        accA[0][1] = MFMA_BF16(a0, q1, accA[0][1]);
        accA[1][0] = MFMA_BF16(a1, q0, accA[1][0]);
        accA[1][1] = MFMA_BF16(a1, q1, accA[1][1]);
        accB[0][0] = MFMA_BF16(a0, u0, accB[0][0]);
        accB[0][1] = MFMA_BF16(a0, u1, accB[0][1]);
        accB[1][0] = MFMA_BF16(a1, u0, accB[1][0]);
        accB[1][1] = MFMA_BF16(a1, u1, accB[1][1]);
    }

    #pragma unroll
    for (int mr = 0; mr < 2; mr++) {
        const int tbase = t0 + wm * 32 + mr * 16 + lg * 4;
        ushort4 c4[2];
        #pragma unroll
        for (int nr = 0; nr < 2; nr++) {
            int d = d0 + wn * 32 + nr * 16 + lr;
            c4[nr] = *(const ushort4*)&CtT[((size_t)b * DD + d) * TT + tbase];
        }
        #pragma unroll
        for (int reg = 0; reg < 4; reg++) {
            int t = tbase + reg;
            float r = rowrcp[(size_t)b * TT + t];
            float* op = out + ((size_t)b * TT + t) * (4 * DD);
            #pragma unroll
            for (int nr = 0; nr < 2; nr++) {
                int d = d0 + wn * 32 + nr * 16 + lr;
                float cv = bf2f(((const u16*)&c4[nr])[reg]);
                float av = accA[mr][nr][reg] * r;
                float bv = accB[mr][nr][reg] * r;
                op[d]          = cv;
                op[DD + d]     = av;
                op[2 * DD + d] = cv * av;
                op[3 * DD + d] = cv * bv;
            }
        }
    }
}

// ---------------------------------------------------------------------------
extern "C" void kernel_launch(void* const* d_in, const int* in_sizes, int n_in,
                              void* d_out, int out_size, void* d_ws, size_t ws_size,
                              hipStream_t stream) {
    const float* C = (const float*)d_in[0];
    const float* Q = (const float*)d_in[1];
    const float* w = (const float*)d_in[2];
    float* out = (float*)d_out;
    float* p = (float*)d_ws;

    u16* Xg  = (u16*)p;     p += (size_t)BB * TT * JJ / 2;   // 8.4 MB
    u16* CtT = (u16*)p;     p += (size_t)BB * DD * TT / 2;   // 16.8 MB
    u16* Qt  = (u16*)p;     p += (size_t)BB * DD * JJ / 2;   // 2.1 MB
    u16* Qhi = (u16*)p;     p += (size_t)BB * JJ * DD / 2;
    u16* Qlo = (u16*)p;     p += (size_t)BB * JJ * DD / 2;
    u16* Tt  = (u16*)p;     p += (size_t)BB * DD * JJ / 2;
    float* ch     = p;      p += BB * TT;
    float* qu     = p;      p += BB * JJ;
    float* rowmax = p;      p += BB * TT;
    float* rowrcp = p;      p += BB * TT;
    float* er     = p;      p += BB * TT;
    float* ec     = p;      p += BB * JJ;
    float* pm     = p;      p += (size_t)BB * 16 * JJ;
    float* ps     = p;      p += (size_t)BB * 16 * JJ;

    k_cprep <<<dim3(TT / 64, BB), dim3(256), 0, stream>>>(C, w, ch, CtT);
    k_qprep <<<dim3(BB), dim3(256), 0, stream>>>(Q, w, qu, Qhi, Qlo, Qt);
    k_S     <<<dim3(TT / 64, BB), dim3(256), 0, stream>>>(C, Qhi, Qlo, w, ch, qu, Xg, rowmax, rowrcp, pm, ps);
    k_colred<<<dim3(BB), dim3(256), 0, stream>>>(pm, ps, rowmax, er, ec);
    k_tmp   <<<dim3(64), dim3(256), 0, stream>>>(Xg, CtT, er, ec, Tt);
    k_out   <<<dim3(BB * 64), dim3(256), 0, stream>>>(Xg, Qt, Tt, CtT, rowrcp, out);
}

// Round 6
// 119.138 us; speedup vs baseline: 1.1597x; 1.1597x over previous
//
#include <hip/hip_runtime.h>
#include <math.h>

#define BB 32
#define TT 1024
#define JJ 128
#define DD 256

typedef unsigned short u16;
typedef short s16x8 __attribute__((ext_vector_type(8)));
typedef float f32x4 __attribute__((ext_vector_type(4)));

#define MFMA_BF16(a, b, c) __builtin_amdgcn_mfma_f32_16x16x32_bf16((a), (b), (c), 0, 0, 0)

__device__ inline u16 f2bf(float f) {
    unsigned int u = __float_as_uint(f);
    u += 0x7FFFu + ((u >> 16) & 1u);
    return (u16)(u >> 16);
}
__device__ inline float bf2f(u16 h) {
    return __uint_as_float(((unsigned int)h) << 16);
}

// ---------------------------------------------------------------------------
// K0: per half-batch (64 j rows): qu[j] = Q[j,:]·w_u ; Qhi/Qlo[j,d] split
// bf16 ; Qt[d,j] bf16 transposed. One Q read serves all.
// ---------------------------------------------------------------------------
__global__ __launch_bounds__(256) void k_qprep(const float* __restrict__ Q,
                                               const float* __restrict__ w,
                                               float* __restrict__ qu,
                                               u16* __restrict__ Qhi,
                                               u16* __restrict__ Qlo,
                                               u16* __restrict__ Qt) {
    const int b = blockIdx.x >> 1, jh = blockIdx.x & 1;
    const int tid = threadIdx.x;
    __shared__ float sW[256];
    __shared__ __align__(16) u16 sTr[256 * 72];   // [d][j-local] stride 72
    sW[tid] = w[DD + tid];
    __syncthreads();
    const int jj = tid >> 2, s = tid & 3;         // 64 j x 4 d-segs
    const int j = jh * 64 + jj;
    const float* qp = Q + ((size_t)b * JJ + j) * DD + s * 64;
    u16* hp = Qhi + ((size_t)b * JJ + j) * DD + s * 64;
    u16* lp = Qlo + ((size_t)b * JJ + j) * DD + s * 64;
    float dot = 0.f;
    #pragma unroll
    for (int q = 0; q < 16; q++) {
        float4 v = *(const float4*)(qp + q * 4);
        const float* wq = &sW[s * 64 + q * 4];
        dot += v.x * wq[0] + v.y * wq[1] + v.z * wq[2] + v.w * wq[3];
        ushort4 h, l;
        h.x = f2bf(v.x); l.x = f2bf(v.x - bf2f(h.x));
        h.y = f2bf(v.y); l.y = f2bf(v.y - bf2f(h.y));
        h.z = f2bf(v.z); l.z = f2bf(v.z - bf2f(h.z));
        h.w = f2bf(v.w); l.w = f2bf(v.w - bf2f(h.w));
        *(ushort4*)(hp + q * 4) = h;
        *(ushort4*)(lp + q * 4) = l;
        int d = s * 64 + q * 4;
        sTr[(d + 0) * 72 + jj] = h.x;
        sTr[(d + 1) * 72 + jj] = h.y;
        sTr[(d + 2) * 72 + jj] = h.z;
        sTr[(d + 3) * 72 + jj] = h.w;
    }
    dot += __shfl_xor(dot, 1, 64);
    dot += __shfl_xor(dot, 2, 64);
    if (s == 0) qu[b * JJ + j] = dot;
    __syncthreads();
    // readback: one d row per thread, 64 j contiguous
    const u16* srow = &sTr[tid * 72];
    u16* drow = &Qt[((size_t)b * DD + tid) * JJ + jh * 64];
    #pragma unroll
    for (int q = 0; q < 8; q++) *(uint4*)&drow[q * 8] = *(const uint4*)&srow[q * 8];
}

// ---------------------------------------------------------------------------
// K2 (split-bf16 MFMA): S = ch + qu + (C*w_hu)·Q^T via hi/lo decomposition.
// ch[t] = C[t,:]·w_h computed inline from the same C loads (k_rowdots gone).
// Epilogue: row stats, column partials, X = exp(S - rowmax) bf16.
// 1-D grid, id = bx*32 + b -> id%8 = b%8 (XCD owns batch).
// ---------------------------------------------------------------------------
__global__ __launch_bounds__(256) void k_S(const float* __restrict__ C,
                                           const u16* __restrict__ Qhi,
                                           const u16* __restrict__ Qlo,
                                           const float* __restrict__ w,
                                           const float* __restrict__ qu,
                                           u16* __restrict__ Xg,
                                           float* __restrict__ rowmax,
                                           float* __restrict__ rowrcp,
                                           float* __restrict__ pm,
                                           float* __restrict__ ps) {
    const int id = blockIdx.x;
    const int b  = id & 31;
    const int bx = id >> 5;
    const int t0 = bx * 64;
    const int tid = threadIdx.x;

    union SMem {
        struct { u16 Ah[64 * 72]; u16 Al[64 * 72]; u16 Bh[128 * 72]; u16 Bl[128 * 72]; } g;
        struct { float S[64 * 132]; float RM[64]; float PM2[256]; float PS2[256]; } e;
    };
    __shared__ __align__(16) SMem sm;
    __shared__ float sCH[64];
    __shared__ float sQU[128];

    if (tid < 128) sQU[tid] = qu[b * JJ + tid];

    const float* whu = w + 2 * DD;
    const float* Cb  = C + ((size_t)b * TT + t0) * DD;

    const int lane = tid & 63, wv = tid >> 6;
    const int wm = wv >> 1, wn = wv & 1;
    const int lr = lane & 15, lg = lane >> 4;

    f32x4 zero4 = {0.f, 0.f, 0.f, 0.f};
    f32x4 acc[2][4];
    #pragma unroll
    for (int m = 0; m < 2; m++)
        #pragma unroll
        for (int n = 0; n < 4; n++) acc[m][n] = zero4;

    const int tA = tid >> 2, sA = (tid & 3) * 16;
    const int jB = tid >> 1, sB = (tid & 1) * 32;
    float chdot = 0.f;

    for (int kc = 0; kc < DD; kc += 64) {
        __syncthreads();
        {   // stage A: (C*w_hu)[64t][64k] -> hi/lo bf16; accumulate ch dot
            const float* cp  = Cb + (size_t)tA * DD + kc + sA;
            const float* wp  = whu + kc + sA;
            const float* whp = w + kc + sA;
            float cc[16], ww[16], wh[16];
            #pragma unroll
            for (int q = 0; q < 4; q++) {
                *(float4*)&cc[q * 4] = *(const float4*)(cp + q * 4);
                *(float4*)&ww[q * 4] = *(const float4*)(wp + q * 4);
                *(float4*)&wh[q * 4] = *(const float4*)(whp + q * 4);
            }
            u16 hi16[16], lo16[16];
            #pragma unroll
            for (int u = 0; u < 16; u++) {
                chdot += cc[u] * wh[u];
                float v = cc[u] * ww[u];
                u16 h = f2bf(v);
                hi16[u] = h;
                lo16[u] = f2bf(v - bf2f(h));
            }
            int o = tA * 72 + sA;
            *(uint4*)&sm.g.Ah[o]     = *(uint4*)&hi16[0];
            *(uint4*)&sm.g.Ah[o + 8] = *(uint4*)&hi16[8];
            *(uint4*)&sm.g.Al[o]     = *(uint4*)&lo16[0];
            *(uint4*)&sm.g.Al[o + 8] = *(uint4*)&lo16[8];
        }
        {   // stage B: Qhi/Qlo[128j][64k] (pure copies)
            const uint4* qh = (const uint4*)&Qhi[((size_t)b * JJ + jB) * DD + kc + sB];
            const uint4* ql = (const uint4*)&Qlo[((size_t)b * JJ + jB) * DD + kc + sB];
            uint4* dh = (uint4*)&sm.g.Bh[jB * 72 + sB];
            uint4* dl = (uint4*)&sm.g.Bl[jB * 72 + sB];
            #pragma unroll
            for (int q = 0; q < 4; q++) { dh[q] = qh[q]; dl[q] = ql[q]; }
        }
        __syncthreads();
        #pragma unroll
        for (int ks = 0; ks < 2; ks++) {
            const int ko = ks * 32 + lg * 8;
            s16x8 ah[2], al[2], bh[4], bl[4];
            #pragma unroll
            for (int m = 0; m < 2; m++) {
                ah[m] = *(const s16x8*)&sm.g.Ah[(wm * 32 + m * 16 + lr) * 72 + ko];
                al[m] = *(const s16x8*)&sm.g.Al[(wm * 32 + m * 16 + lr) * 72 + ko];
            }
            #pragma unroll
            for (int n = 0; n < 4; n++) {
                bh[n] = *(const s16x8*)&sm.g.Bh[(wn * 64 + n * 16 + lr) * 72 + ko];
                bl[n] = *(const s16x8*)&sm.g.Bl[(wn * 64 + n * 16 + lr) * 72 + ko];
            }
            #pragma unroll
            for (int m = 0; m < 2; m++)
                #pragma unroll
                for (int n = 0; n < 4; n++) {
                    f32x4 t = acc[m][n];
                    t = MFMA_BF16(ah[m], bh[n], t);
                    t = MFMA_BF16(ah[m], bl[n], t);
                    t = MFMA_BF16(al[m], bh[n], t);
                    acc[m][n] = t;
                }
        }
    }

    // finalize ch: combine 4 d-segment partials per t-row
    chdot += __shfl_xor(chdot, 1, 64);
    chdot += __shfl_xor(chdot, 2, 64);
    if ((tid & 3) == 0) sCH[tid >> 2] = chdot;

    // ---- epilogue ----
    __syncthreads();
    #pragma unroll
    for (int m = 0; m < 2; m++) {
        int row0 = wm * 32 + m * 16 + lg * 4;
        #pragma unroll
        for (int n = 0; n < 4; n++) {
            int col = wn * 64 + n * 16 + lr;
            float qv = sQU[col];
            #pragma unroll
            for (int reg = 0; reg < 4; reg++)
                sm.e.S[(row0 + reg) * 132 + col] = acc[m][n][reg] + sCH[row0 + reg] + qv;
        }
    }
    __syncthreads();
    {   // row stats: 4 threads per row
        int r = tid >> 2, s = tid & 3;
        float v[32];
        const float* Sr = &sm.e.S[r * 132 + s * 32];
        #pragma unroll
        for (int q = 0; q < 8; q++) *(float4*)&v[q * 4] = *(const float4*)&Sr[q * 4];
        float mx = v[0];
        #pragma unroll
        for (int u = 1; u < 32; u++) mx = fmaxf(mx, v[u]);
        mx = fmaxf(mx, __shfl_xor(mx, 1, 64));
        mx = fmaxf(mx, __shfl_xor(mx, 2, 64));
        float sum = 0.f;
        #pragma unroll
        for (int u = 0; u < 32; u++) sum += __expf(v[u] - mx);
        sum += __shfl_xor(sum, 1, 64);
        sum += __shfl_xor(sum, 2, 64);
        if (s == 0) {
            sm.e.RM[r] = mx;
            rowmax[(size_t)b * TT + t0 + r] = mx;
            rowrcp[(size_t)b * TT + t0 + r] = 1.0f / sum;
        }
    }
    {   // column partials (two t-halves per column)
        int j = tid & 127, h = tid >> 7;
        float cm = -1e30f;
        #pragma unroll
        for (int k = 0; k < 32; k++) cm = fmaxf(cm, sm.e.S[(h * 32 + k) * 132 + j]);
        float cs = 0.f;
        #pragma unroll
        for (int k = 0; k < 32; k++) cs += __expf(sm.e.S[(h * 32 + k) * 132 + j] - cm);
        sm.e.PM2[h * 128 + j] = cm;
        sm.e.PS2[h * 128 + j] = cs;
    }
    __syncthreads();
    if (tid < 128) {
        float m0 = sm.e.PM2[tid], m1 = sm.e.PM2[128 + tid];
        float M = fmaxf(m0, m1);
        float S2 = sm.e.PS2[tid] * __expf(m0 - M) + sm.e.PS2[128 + tid] * __expf(m1 - M);
        pm[((size_t)b * 16 + bx) * JJ + tid] = M;
        ps[((size_t)b * 16 + bx) * JJ + tid] = S2;
    }
    // X = exp(S - rowmax) bf16
    #pragma unroll
    for (int i = 0; i < 4; i++) {
        int c = tid + 256 * i;
        int row = c >> 4, j0 = (c & 15) * 8;
        float rm = sm.e.RM[row];
        float vv[8];
        *(float4*)&vv[0] = *(const float4*)&sm.e.S[row * 132 + j0];
        *(float4*)&vv[4] = *(const float4*)&sm.e.S[row * 132 + j0 + 4];
        u16 xp[8];
        #pragma unroll
        for (int u = 0; u < 8; u++) xp[u] = f2bf(__expf(vv[u] - rm));
        *(uint4*)&Xg[((size_t)b * TT + t0 + row) * JJ + j0] = *(uint4*)&xp[0];
    }
}

// ---------------------------------------------------------------------------
// K3: per-batch reduce: K_b = max_t rowmax; er[t] = exp(rowmax - K_b);
// ec[j] = exp(K_b - colmax)/colsum.
// ---------------------------------------------------------------------------
__global__ __launch_bounds__(256) void k_colred(const float* __restrict__ pm,
                                                const float* __restrict__ ps,
                                                const float* __restrict__ rowmax,
                                                float* __restrict__ er,
                                                float* __restrict__ ec) {
    const int b = blockIdx.x;
    const int tid = threadIdx.x;
    __shared__ float sW[4];
    float m = -1e30f;
    #pragma unroll
    for (int k = 0; k < 4; k++) m = fmaxf(m, rowmax[(size_t)b * TT + tid + 256 * k]);
    #pragma unroll
    for (int off = 32; off; off >>= 1) m = fmaxf(m, __shfl_xor(m, off, 64));
    if ((tid & 63) == 0) sW[tid >> 6] = m;
    __syncthreads();
    const float K = fmaxf(fmaxf(sW[0], sW[1]), fmaxf(sW[2], sW[3]));
    #pragma unroll
    for (int k = 0; k < 4; k++) {
        int i = tid + 256 * k;
        er[(size_t)b * TT + i] = __expf(rowmax[(size_t)b * TT + i] - K);
    }
    if (tid < JJ) {
        float cm = -1e30f;
        #pragma unroll
        for (int tb = 0; tb < 16; tb++) cm = fmaxf(cm, pm[((size_t)b * 16 + tb) * JJ + tid]);
        float cs = 0.f;
        #pragma unroll
        for (int tb = 0; tb < 16; tb++)
            cs += ps[((size_t)b * 16 + tb) * JJ + tid] * __expf(pm[((size_t)b * 16 + tb) * JJ + tid] - cm);
        ec[b * JJ + tid] = __expf(K - cm) / cs;
    }
}

// ---------------------------------------------------------------------------
// K4 (MFMA): Tt[b,d,j] = sum_t G[t,j]*C[t,d], G = X*er[t]*ec[j].
// 8 d-splits (256 blocks); id = dh*32 + b -> id%8 = b%8 so all 8 d-blocks of
// a batch share one XCD (X fetched once into L2, C columns are disjoint).
// ---------------------------------------------------------------------------
__global__ __launch_bounds__(256) void k_tmp(const u16* __restrict__ Xg,
                                             const float* __restrict__ C,
                                             const float* __restrict__ er,
                                             const float* __restrict__ ec,
                                             u16* __restrict__ Tt) {
    const int id = blockIdx.x;
    const int b = id & 31, dh = id >> 5;          // dh in 0..7
    const int d0 = dh * 32;
    const int tid = threadIdx.x;
    __shared__ __align__(16) u16 sG[128 * 72];    // [j][t] stride 72
    __shared__ __align__(16) u16 sCt[32 * 72];    // [d][t] stride 72
    __shared__ float sEC[128];
    if (tid < 128) sEC[tid] = ec[b * JJ + tid];
    const int lane = tid & 63, wv = tid >> 6;
    const int lr = lane & 15, lg = lane >> 4;
    f32x4 zero4 = {0.f, 0.f, 0.f, 0.f};
    f32x4 acc[2][2];
    acc[0][0] = zero4; acc[0][1] = zero4; acc[1][0] = zero4; acc[1][1] = zero4;

    for (int tt = 0; tt < TT; tt += 64) {
        __syncthreads();
        // stage G^T = X * er * ec (bf16), [j][t]
        #pragma unroll
        for (int i = 0; i < 4; i++) {
            int c = tid + 256 * i;
            int trow = c >> 4, j0 = (c & 15) * 8;
            float e = er[(size_t)b * TT + tt + trow];
            uint4 xv = *(const uint4*)&Xg[((size_t)b * TT + tt + trow) * JJ + j0];
            const u16* xp = (const u16*)&xv;
            #pragma unroll
            for (int u = 0; u < 8; u++)
                sG[(j0 + u) * 72 + trow] = f2bf(bf2f(xp[u]) * e * sEC[j0 + u]);
        }
        // stage C^T from fp32 C (32 d columns of this block)
        #pragma unroll
        for (int i = 0; i < 2; i++) {
            int c = tid + 256 * i;
            int trow = c >> 3, dcl = (c & 7) * 4;
            float4 cv = *(const float4*)&C[((size_t)b * TT + tt + trow) * DD + d0 + dcl];
            sCt[(dcl + 0) * 72 + trow] = f2bf(cv.x);
            sCt[(dcl + 1) * 72 + trow] = f2bf(cv.y);
            sCt[(dcl + 2) * 72 + trow] = f2bf(cv.z);
            sCt[(dcl + 3) * 72 + trow] = f2bf(cv.w);
        }
        __syncthreads();
        #pragma unroll
        for (int ks = 0; ks < 2; ks++) {
            int ko = ks * 32 + lg * 8;
            s16x8 a0 = *(const s16x8*)&sG[(wv * 32 + lr) * 72 + ko];
            s16x8 a1 = *(const s16x8*)&sG[(wv * 32 + 16 + lr) * 72 + ko];
            s16x8 b0 = *(const s16x8*)&sCt[(lr) * 72 + ko];
            s16x8 b1 = *(const s16x8*)&sCt[(16 + lr) * 72 + ko];
            acc[0][0] = MFMA_BF16(a0, b0, acc[0][0]);
            acc[0][1] = MFMA_BF16(a0, b1, acc[0][1]);
            acc[1][0] = MFMA_BF16(a1, b0, acc[1][0]);
            acc[1][1] = MFMA_BF16(a1, b1, acc[1][1]);
        }
    }
    #pragma unroll
    for (int mr = 0; mr < 2; mr++)
        #pragma unroll
        for (int nr = 0; nr < 2; nr++)
            #pragma unroll
            for (int reg = 0; reg < 4; reg++) {
                int j = wv * 32 + mr * 16 + lg * 4 + reg;
                int d = d0 + nr * 16 + lr;
                Tt[((size_t)b * DD + d) * JJ + j] = f2bf(acc[mr][nr][reg]);
            }
}

// ---------------------------------------------------------------------------
// K5 (MFMA): A = (X·rowrcp)·Q, Bm = (X·rowrcp)·tmp; out = [C, A, C*A, C*Bm].
// id = k*32 + b -> id%8 = b%8: the whole batch (X, Qt, Tt) lives on one XCD.
// ---------------------------------------------------------------------------
__global__ __launch_bounds__(256) void k_out(const u16* __restrict__ Xg,
                                             const u16* __restrict__ Qt,
                                             const u16* __restrict__ Tt,
                                             const float* __restrict__ C,
                                             const float* __restrict__ rowrcp,
                                             float* __restrict__ out) {
    const int id = blockIdx.x;
    const int b = id & 31, k = id >> 5;
    const int dc = k & 3, tc = k >> 2;
    const int t0 = tc * 64, d0 = dc * 64;
    const int tid = threadIdx.x;
    __shared__ __align__(16) u16 sX[64 * 136];
    __shared__ __align__(16) u16 sQ[64 * 136];
    __shared__ __align__(16) u16 sT[64 * 136];
    const size_t xbase = ((size_t)b * TT + t0) * JJ;
    const size_t qbase = ((size_t)b * DD + d0) * JJ;
    #pragma unroll
    for (int i = 0; i < 4; i++) {
        int c = tid + 256 * i;
        int row = c >> 4, col = (c & 15) * 8;
        int lo = row * 136 + col;
        *(uint4*)&sX[lo] = *(const uint4*)&Xg[xbase + (size_t)row * JJ + col];
        *(uint4*)&sQ[lo] = *(const uint4*)&Qt[qbase + (size_t)row * JJ + col];
        *(uint4*)&sT[lo] = *(const uint4*)&Tt[qbase + (size_t)row * JJ + col];
    }
    __syncthreads();
    const int lane = tid & 63, wv = tid >> 6;
    const int wm = wv >> 1, wn = wv & 1;
    const int lr = lane & 15, lg = lane >> 4;
    f32x4 zero4 = {0.f, 0.f, 0.f, 0.f};
    f32x4 accA[2][2], accB[2][2];
    #pragma unroll
    for (int mr = 0; mr < 2; mr++)
        #pragma unroll
        for (int nr = 0; nr < 2; nr++) { accA[mr][nr] = zero4; accB[mr][nr] = zero4; }

    #pragma unroll
    for (int ks = 0; ks < 4; ks++) {
        int kc = ks * 32 + lg * 8;
        s16x8 a0 = *(const s16x8*)&sX[(wm * 32 + lr) * 136 + kc];
        s16x8 a1 = *(const s16x8*)&sX[(wm * 32 + 16 + lr) * 136 + kc];
        s16x8 q0 = *(const s16x8*)&sQ[(wn * 32 + lr) * 136 + kc];
        s16x8 q1 = *(const s16x8*)&sQ[(wn * 32 + 16 + lr) * 136 + kc];
        s16x8 u0 = *(const s16x8*)&sT[(wn * 32 + lr) * 136 + kc];
        s16x8 u1 = *(const s16x8*)&sT[(wn * 32 + 16 + lr) * 136 + kc];
        accA[0][0] = MFMA_BF16(a0, q0, accA[0][0]);
        accA[0][1] = MFMA_BF16(a0, q1, accA[0][1]);
        accA[1][0] = MFMA_BF16(a1, q0, accA[1][0]);
        accA[1][1] = MFMA_BF16(a1, q1, accA[1][1]);
        accB[0][0] = MFMA_BF16(a0, u0, accB[0][0]);
        accB[0][1] = MFMA_BF16(a0, u1, accB[0][1]);
        accB[1][0] = MFMA_BF16(a1, u0, accB[1][0]);
        accB[1][1] = MFMA_BF16(a1, u1, accB[1][1]);
    }

    #pragma unroll
    for (int mr = 0; mr < 2; mr++) {
        #pragma unroll
        for (int reg = 0; reg < 4; reg++) {
            int t = t0 + wm * 32 + mr * 16 + lg * 4 + reg;
            float r = rowrcp[(size_t)b * TT + t];
            const float* Cp = C + ((size_t)b * TT + t) * DD;
            float* op = out + ((size_t)b * TT + t) * (4 * DD);
            #pragma unroll
            for (int nr = 0; nr < 2; nr++) {
                int d = d0 + wn * 32 + nr * 16 + lr;
                float cv = Cp[d];
                float av = accA[mr][nr][reg] * r;
                float bv = accB[mr][nr][reg] * r;
                op[d]          = cv;
                op[DD + d]     = av;
                op[2 * DD + d] = cv * av;
                op[3 * DD + d] = cv * bv;
            }
        }
    }
}

// ---------------------------------------------------------------------------
extern "C" void kernel_launch(void* const* d_in, const int* in_sizes, int n_in,
                              void* d_out, int out_size, void* d_ws, size_t ws_size,
                              hipStream_t stream) {
    const float* C = (const float*)d_in[0];
    const float* Q = (const float*)d_in[1];
    const float* w = (const float*)d_in[2];
    float* out = (float*)d_out;
    float* p = (float*)d_ws;

    u16* Xg  = (u16*)p;     p += (size_t)BB * TT * JJ / 2;   // 8.4 MB
    u16* Qt  = (u16*)p;     p += (size_t)BB * DD * JJ / 2;
    u16* Qhi = (u16*)p;     p += (size_t)BB * JJ * DD / 2;
    u16* Qlo = (u16*)p;     p += (size_t)BB * JJ * DD / 2;
    u16* Tt  = (u16*)p;     p += (size_t)BB * DD * JJ / 2;
    float* qu     = p;      p += BB * JJ;
    float* rowmax = p;      p += BB * TT;
    float* rowrcp = p;      p += BB * TT;
    float* er     = p;      p += BB * TT;
    float* ec     = p;      p += BB * JJ;
    float* pm     = p;      p += (size_t)BB * 16 * JJ;
    float* ps     = p;      p += (size_t)BB * 16 * JJ;

    k_qprep <<<dim3(BB * 2), dim3(256), 0, stream>>>(Q, w, qu, Qhi, Qlo, Qt);
    k_S     <<<dim3(16 * BB), dim3(256), 0, stream>>>(C, Qhi, Qlo, w, qu, Xg, rowmax, rowrcp, pm, ps);
    k_colred<<<dim3(BB), dim3(256), 0, stream>>>(pm, ps, rowmax, er, ec);
    k_tmp   <<<dim3(8 * BB), dim3(256), 0, stream>>>(Xg, C, er, ec, Tt);
    k_out   <<<dim3(64 * BB), dim3(256), 0, stream>>>(Xg, Qt, Tt, C, rowrcp, out);
}

// Round 7
// 115.680 us; speedup vs baseline: 1.1944x; 1.0299x over previous
//
#include <hip/hip_runtime.h>
#include <math.h>

#define BB 32
#define TT 1024
#define JJ 128
#define DD 256

typedef unsigned short u16;
typedef short s16x8 __attribute__((ext_vector_type(8)));
typedef float f32x4 __attribute__((ext_vector_type(4)));

#define MFMA_BF16(a, b, c) __builtin_amdgcn_mfma_f32_16x16x32_bf16((a), (b), (c), 0, 0, 0)

__device__ inline u16 f2bf(float f) {
    unsigned int u = __float_as_uint(f);
    u += 0x7FFFu + ((u >> 16) & 1u);
    return (u16)(u >> 16);
}
__device__ inline float bf2f(u16 h) {
    return __uint_as_float(((unsigned int)h) << 16);
}

// ---------------------------------------------------------------------------
// K0: per half-batch (64 j rows): qu[j] = Q[j,:]·w_u ; Qhi/Qlo[j,d] split
// bf16 ; Qt[d,j] bf16 transposed. One Q read serves all.
// ---------------------------------------------------------------------------
__global__ __launch_bounds__(256) void k_qprep(const float* __restrict__ Q,
                                               const float* __restrict__ w,
                                               float* __restrict__ qu,
                                               u16* __restrict__ Qhi,
                                               u16* __restrict__ Qlo,
                                               u16* __restrict__ Qt) {
    const int b = blockIdx.x >> 1, jh = blockIdx.x & 1;
    const int tid = threadIdx.x;
    __shared__ float sW[256];
    __shared__ __align__(16) u16 sTr[256 * 72];   // [d][j-local] stride 72
    sW[tid] = w[DD + tid];
    __syncthreads();
    const int jj = tid >> 2, s = tid & 3;         // 64 j x 4 d-segs
    const int j = jh * 64 + jj;
    const float* qp = Q + ((size_t)b * JJ + j) * DD + s * 64;
    u16* hp = Qhi + ((size_t)b * JJ + j) * DD + s * 64;
    u16* lp = Qlo + ((size_t)b * JJ + j) * DD + s * 64;
    float dot = 0.f;
    #pragma unroll
    for (int q = 0; q < 16; q++) {
        float4 v = *(const float4*)(qp + q * 4);
        const float* wq = &sW[s * 64 + q * 4];
        dot += v.x * wq[0] + v.y * wq[1] + v.z * wq[2] + v.w * wq[3];
        ushort4 h, l;
        h.x = f2bf(v.x); l.x = f2bf(v.x - bf2f(h.x));
        h.y = f2bf(v.y); l.y = f2bf(v.y - bf2f(h.y));
        h.z = f2bf(v.z); l.z = f2bf(v.z - bf2f(h.z));
        h.w = f2bf(v.w); l.w = f2bf(v.w - bf2f(h.w));
        *(ushort4*)(hp + q * 4) = h;
        *(ushort4*)(lp + q * 4) = l;
        int d = s * 64 + q * 4;
        sTr[(d + 0) * 72 + jj] = h.x;
        sTr[(d + 1) * 72 + jj] = h.y;
        sTr[(d + 2) * 72 + jj] = h.z;
        sTr[(d + 3) * 72 + jj] = h.w;
    }
    dot += __shfl_xor(dot, 1, 64);
    dot += __shfl_xor(dot, 2, 64);
    if (s == 0) qu[b * JJ + j] = dot;
    __syncthreads();
    const u16* srow = &sTr[tid * 72];
    u16* drow = &Qt[((size_t)b * DD + tid) * JJ + jh * 64];
    #pragma unroll
    for (int q = 0; q < 8; q++) *(uint4*)&drow[q * 8] = *(const uint4*)&srow[q * 8];
}

// ---------------------------------------------------------------------------
// K2 (split-bf16 MFMA): S = ch + qu + (C*w_hu)·Q^T via hi/lo decomposition.
// ch computed inline. Epilogue v2: row stats with in-place exp (S LDS becomes
// X fp32), X-write reuses it (no re-exp), column partials are pure fma:
// ps[j] = sum_t X[t,j]*exp(rowmax[t]-M_blk)  (scalar pm = M_blk per block).
// colmax eliminated algebraically (cancels in Y/sumY).
// ---------------------------------------------------------------------------
__global__ __launch_bounds__(256) void k_S(const float* __restrict__ C,
                                           const u16* __restrict__ Qhi,
                                           const u16* __restrict__ Qlo,
                                           const float* __restrict__ w,
                                           const float* __restrict__ qu,
                                           u16* __restrict__ Xg,
                                           float* __restrict__ rowmax,
                                           float* __restrict__ rowrcp,
                                           float* __restrict__ pm,
                                           float* __restrict__ ps) {
    const int id = blockIdx.x;
    const int b  = id & 31;
    const int bx = id >> 5;
    const int t0 = bx * 64;
    const int tid = threadIdx.x;

    union SMem {
        struct { u16 Ah[64 * 72]; u16 Al[64 * 72]; u16 Bh[128 * 72]; u16 Bl[128 * 72]; } g;
        struct { float S[64 * 132]; float RM[64]; float W[4]; float ER[64]; float PS2[256]; } e;
    };
    __shared__ __align__(16) SMem sm;
    __shared__ float sCH[64];
    __shared__ float sQU[128];

    if (tid < 128) sQU[tid] = qu[b * JJ + tid];

    const float* whu = w + 2 * DD;
    const float* Cb  = C + ((size_t)b * TT + t0) * DD;

    const int lane = tid & 63, wv = tid >> 6;
    const int wm = wv >> 1, wn = wv & 1;
    const int lr = lane & 15, lg = lane >> 4;

    f32x4 zero4 = {0.f, 0.f, 0.f, 0.f};
    f32x4 acc[2][4];
    #pragma unroll
    for (int m = 0; m < 2; m++)
        #pragma unroll
        for (int n = 0; n < 4; n++) acc[m][n] = zero4;

    const int tA = tid >> 2, sA = (tid & 3) * 16;
    const int jB = tid >> 1, sB = (tid & 1) * 32;
    float chdot = 0.f;

    for (int kc = 0; kc < DD; kc += 64) {
        __syncthreads();
        {   // stage A: (C*w_hu)[64t][64k] -> hi/lo bf16; accumulate ch dot
            const float* cp  = Cb + (size_t)tA * DD + kc + sA;
            const float* wp  = whu + kc + sA;
            const float* whp = w + kc + sA;
            float cc[16], ww[16], wh[16];
            #pragma unroll
            for (int q = 0; q < 4; q++) {
                *(float4*)&cc[q * 4] = *(const float4*)(cp + q * 4);
                *(float4*)&ww[q * 4] = *(const float4*)(wp + q * 4);
                *(float4*)&wh[q * 4] = *(const float4*)(whp + q * 4);
            }
            u16 hi16[16], lo16[16];
            #pragma unroll
            for (int u = 0; u < 16; u++) {
                chdot += cc[u] * wh[u];
                float v = cc[u] * ww[u];
                u16 h = f2bf(v);
                hi16[u] = h;
                lo16[u] = f2bf(v - bf2f(h));
            }
            int o = tA * 72 + sA;
            *(uint4*)&sm.g.Ah[o]     = *(uint4*)&hi16[0];
            *(uint4*)&sm.g.Ah[o + 8] = *(uint4*)&hi16[8];
            *(uint4*)&sm.g.Al[o]     = *(uint4*)&lo16[0];
            *(uint4*)&sm.g.Al[o + 8] = *(uint4*)&lo16[8];
        }
        {   // stage B: Qhi/Qlo[128j][64k] (pure copies)
            const uint4* qh = (const uint4*)&Qhi[((size_t)b * JJ + jB) * DD + kc + sB];
            const uint4* ql = (const uint4*)&Qlo[((size_t)b * JJ + jB) * DD + kc + sB];
            uint4* dh = (uint4*)&sm.g.Bh[jB * 72 + sB];
            uint4* dl = (uint4*)&sm.g.Bl[jB * 72 + sB];
            #pragma unroll
            for (int q = 0; q < 4; q++) { dh[q] = qh[q]; dl[q] = ql[q]; }
        }
        __syncthreads();
        #pragma unroll
        for (int ks = 0; ks < 2; ks++) {
            const int ko = ks * 32 + lg * 8;
            s16x8 ah[2], al[2], bh[4], bl[4];
            #pragma unroll
            for (int m = 0; m < 2; m++) {
                ah[m] = *(const s16x8*)&sm.g.Ah[(wm * 32 + m * 16 + lr) * 72 + ko];
                al[m] = *(const s16x8*)&sm.g.Al[(wm * 32 + m * 16 + lr) * 72 + ko];
            }
            #pragma unroll
            for (int n = 0; n < 4; n++) {
                bh[n] = *(const s16x8*)&sm.g.Bh[(wn * 64 + n * 16 + lr) * 72 + ko];
                bl[n] = *(const s16x8*)&sm.g.Bl[(wn * 64 + n * 16 + lr) * 72 + ko];
            }
            #pragma unroll
            for (int m = 0; m < 2; m++)
                #pragma unroll
                for (int n = 0; n < 4; n++) {
                    f32x4 t = acc[m][n];
                    t = MFMA_BF16(ah[m], bh[n], t);
                    t = MFMA_BF16(ah[m], bl[n], t);
                    t = MFMA_BF16(al[m], bh[n], t);
                    acc[m][n] = t;
                }
        }
    }

    // finalize ch: combine 4 d-segment partials per t-row
    chdot += __shfl_xor(chdot, 1, 64);
    chdot += __shfl_xor(chdot, 2, 64);
    if ((tid & 3) == 0) sCH[tid >> 2] = chdot;

    // ---- epilogue ----
    __syncthreads();
    #pragma unroll
    for (int m = 0; m < 2; m++) {
        int row0 = wm * 32 + m * 16 + lg * 4;
        #pragma unroll
        for (int n = 0; n < 4; n++) {
            int col = wn * 64 + n * 16 + lr;
            float qv = sQU[col];
            #pragma unroll
            for (int reg = 0; reg < 4; reg++)
                sm.e.S[(row0 + reg) * 132 + col] = acc[m][n][reg] + sCH[row0 + reg] + qv;
        }
    }
    __syncthreads();
    {   // pass 1: row stats + in-place exp (S -> X fp32)
        int r = tid >> 2, s = tid & 3;
        float v[32];
        float* Sr = &sm.e.S[r * 132 + s * 32];
        #pragma unroll
        for (int q = 0; q < 8; q++) *(float4*)&v[q * 4] = *(const float4*)&Sr[q * 4];
        float mx = v[0];
        #pragma unroll
        for (int u = 1; u < 32; u++) mx = fmaxf(mx, v[u]);
        mx = fmaxf(mx, __shfl_xor(mx, 1, 64));
        mx = fmaxf(mx, __shfl_xor(mx, 2, 64));
        float sum = 0.f;
        #pragma unroll
        for (int u = 0; u < 32; u++) { v[u] = __expf(v[u] - mx); sum += v[u]; }
        sum += __shfl_xor(sum, 1, 64);
        sum += __shfl_xor(sum, 2, 64);
        #pragma unroll
        for (int q = 0; q < 8; q++) *(float4*)&Sr[q * 4] = *(const float4*)&v[q * 4];
        if (s == 0) {
            sm.e.RM[r] = mx;
            rowmax[(size_t)b * TT + t0 + r] = mx;
            rowrcp[(size_t)b * TT + t0 + r] = 1.0f / sum;
        }
        // block max of rowmax (16 rows per wave; all 4 s-lanes hold row max)
        float wmx = mx;
        wmx = fmaxf(wmx, __shfl_xor(wmx, 4, 64));
        wmx = fmaxf(wmx, __shfl_xor(wmx, 8, 64));
        wmx = fmaxf(wmx, __shfl_xor(wmx, 16, 64));
        wmx = fmaxf(wmx, __shfl_xor(wmx, 32, 64));
        if (lane == 0) sm.e.W[wv] = wmx;
    }
    __syncthreads();
    const float Mb = fmaxf(fmaxf(sm.e.W[0], sm.e.W[1]), fmaxf(sm.e.W[2], sm.e.W[3]));
    if (tid < 64) sm.e.ER[tid] = __expf(sm.e.RM[tid] - Mb);
    // X write: read X fp32 from LDS (no exp), pack bf16
    #pragma unroll
    for (int i = 0; i < 4; i++) {
        int c = tid + 256 * i;
        int row = c >> 4, j0 = (c & 15) * 8;
        float vv[8];
        *(float4*)&vv[0] = *(const float4*)&sm.e.S[row * 132 + j0];
        *(float4*)&vv[4] = *(const float4*)&sm.e.S[row * 132 + j0 + 4];
        u16 xp[8];
        #pragma unroll
        for (int u = 0; u < 8; u++) xp[u] = f2bf(vv[u]);
        *(uint4*)&Xg[((size_t)b * TT + t0 + row) * JJ + j0] = *(uint4*)&xp[0];
    }
    __syncthreads();
    {   // column partials: pure fma against ER (no exp)
        int j = tid & 127, h = tid >> 7;
        float cs = 0.f;
        #pragma unroll
        for (int k = 0; k < 32; k++)
            cs = fmaf(sm.e.S[(h * 32 + k) * 132 + j], sm.e.ER[h * 32 + k], cs);
        sm.e.PS2[h * 128 + j] = cs;
    }
    __syncthreads();
    if (tid < 128) ps[((size_t)b * 16 + bx) * JJ + tid] = sm.e.PS2[tid] + sm.e.PS2[128 + tid];
    if (tid == 0)  pm[b * 16 + bx] = Mb;
}

// ---------------------------------------------------------------------------
// K4 (MFMA): Tt[b,d,j] = sum_t G[t,j]*C[t,d], G = X*er[t]*ec[j].
// Prologue replicates the old k_colred per block (cheap): K = max rowmax,
// er[t] = exp(rowmax-K) in LDS, ec[j] = 1/sum_blk ps[blk][j]*exp(pm[blk]-K).
// id = dh*32 + b -> id%8 = b%8 (XCD owns batch; X L2-resident).
// ---------------------------------------------------------------------------
__global__ __launch_bounds__(256) void k_tmp(const u16* __restrict__ Xg,
                                             const float* __restrict__ C,
                                             const float* __restrict__ rowmax,
                                             const float* __restrict__ pm,
                                             const float* __restrict__ ps,
                                             u16* __restrict__ Tt) {
    const int id = blockIdx.x;
    const int b = id & 31, dh = id >> 5;          // dh in 0..7
    const int d0 = dh * 32;
    const int tid = threadIdx.x;
    __shared__ __align__(16) u16 sG[128 * 72];    // [j][t] stride 72
    __shared__ __align__(16) u16 sCt[32 * 72];    // [d][t] stride 72
    __shared__ float sER[1024];
    __shared__ float sEC[128];
    __shared__ float sPE[16];
    __shared__ float sW2[4];
    const int lane = tid & 63, wv = tid >> 6;

    {   // K_b = max rowmax over batch
        float4 rm4 = *(const float4*)&rowmax[(size_t)b * TT + tid * 4];
        float km = fmaxf(fmaxf(rm4.x, rm4.y), fmaxf(rm4.z, rm4.w));
        #pragma unroll
        for (int off = 1; off < 64; off <<= 1) km = fmaxf(km, __shfl_xor(km, off, 64));
        if (lane == 0) sW2[wv] = km;
        __syncthreads();
        const float K = fmaxf(fmaxf(sW2[0], sW2[1]), fmaxf(sW2[2], sW2[3]));
        float4 e4;
        e4.x = __expf(rm4.x - K);
        e4.y = __expf(rm4.y - K);
        e4.z = __expf(rm4.z - K);
        e4.w = __expf(rm4.w - K);
        *(float4*)&sER[tid * 4] = e4;
        if (tid < 16) sPE[tid] = __expf(pm[b * 16 + tid] - K);
        __syncthreads();
        if (tid < 128) {
            float cy = 0.f;
            #pragma unroll
            for (int blk = 0; blk < 16; blk++)
                cy = fmaf(ps[((size_t)b * 16 + blk) * JJ + tid], sPE[blk], cy);
            sEC[tid] = 1.0f / cy;
        }
    }

    const int lr = lane & 15, lg = lane >> 4;
    f32x4 zero4 = {0.f, 0.f, 0.f, 0.f};
    f32x4 acc[2][2];
    acc[0][0] = zero4; acc[0][1] = zero4; acc[1][0] = zero4; acc[1][1] = zero4;

    for (int tt = 0; tt < TT; tt += 64) {
        __syncthreads();
        // stage G^T = X * er * ec (bf16), [j][t]
        #pragma unroll
        for (int i = 0; i < 4; i++) {
            int c = tid + 256 * i;
            int trow = c >> 4, j0 = (c & 15) * 8;
            float e = sER[tt + trow];
            uint4 xv = *(const uint4*)&Xg[((size_t)b * TT + tt + trow) * JJ + j0];
            const u16* xp = (const u16*)&xv;
            #pragma unroll
            for (int u = 0; u < 8; u++)
                sG[(j0 + u) * 72 + trow] = f2bf(bf2f(xp[u]) * e * sEC[j0 + u]);
        }
        // stage C^T from fp32 C (32 d columns of this block)
        #pragma unroll
        for (int i = 0; i < 2; i++) {
            int c = tid + 256 * i;
            int trow = c >> 3, dcl = (c & 7) * 4;
            float4 cv = *(const float4*)&C[((size_t)b * TT + tt + trow) * DD + d0 + dcl];
            sCt[(dcl + 0) * 72 + trow] = f2bf(cv.x);
            sCt[(dcl + 1) * 72 + trow] = f2bf(cv.y);
            sCt[(dcl + 2) * 72 + trow] = f2bf(cv.z);
            sCt[(dcl + 3) * 72 + trow] = f2bf(cv.w);
        }
        __syncthreads();
        #pragma unroll
        for (int ks = 0; ks < 2; ks++) {
            int ko = ks * 32 + lg * 8;
            s16x8 a0 = *(const s16x8*)&sG[(wv * 32 + lr) * 72 + ko];
            s16x8 a1 = *(const s16x8*)&sG[(wv * 32 + 16 + lr) * 72 + ko];
            s16x8 b0 = *(const s16x8*)&sCt[(lr) * 72 + ko];
            s16x8 b1 = *(const s16x8*)&sCt[(16 + lr) * 72 + ko];
            acc[0][0] = MFMA_BF16(a0, b0, acc[0][0]);
            acc[0][1] = MFMA_BF16(a0, b1, acc[0][1]);
            acc[1][0] = MFMA_BF16(a1, b0, acc[1][0]);
            acc[1][1] = MFMA_BF16(a1, b1, acc[1][1]);
        }
    }
    #pragma unroll
    for (int mr = 0; mr < 2; mr++)
        #pragma unroll
        for (int nr = 0; nr < 2; nr++)
            #pragma unroll
            for (int reg = 0; reg < 4; reg++) {
                int j = wv * 32 + mr * 16 + lg * 4 + reg;
                int d = d0 + nr * 16 + lr;
                Tt[((size_t)b * DD + d) * JJ + j] = f2bf(acc[mr][nr][reg]);
            }
}

// ---------------------------------------------------------------------------
// K5 (MFMA): A = (X·rowrcp)·Q, Bm = (X·rowrcp)·tmp; out = [C, A, C*A, C*Bm].
// id = k*32 + b -> id%8 = b%8: the whole batch (X, Qt, Tt) lives on one XCD.
// ---------------------------------------------------------------------------
__global__ __launch_bounds__(256) void k_out(const u16* __restrict__ Xg,
                                             const u16* __restrict__ Qt,
                                             const u16* __restrict__ Tt,
                                             const float* __restrict__ C,
                                             const float* __restrict__ rowrcp,
                                             float* __restrict__ out) {
    const int id = blockIdx.x;
    const int b = id & 31, k = id >> 5;
    const int dc = k & 3, tc = k >> 2;
    const int t0 = tc * 64, d0 = dc * 64;
    const int tid = threadIdx.x;
    __shared__ __align__(16) u16 sX[64 * 136];
    __shared__ __align__(16) u16 sQ[64 * 136];
    __shared__ __align__(16) u16 sT[64 * 136];
    const size_t xbase = ((size_t)b * TT + t0) * JJ;
    const size_t qbase = ((size_t)b * DD + d0) * JJ;
    #pragma unroll
    for (int i = 0; i < 4; i++) {
        int c = tid + 256 * i;
        int row = c >> 4, col = (c & 15) * 8;
        int lo = row * 136 + col;
        *(uint4*)&sX[lo] = *(const uint4*)&Xg[xbase + (size_t)row * JJ + col];
        *(uint4*)&sQ[lo] = *(const uint4*)&Qt[qbase + (size_t)row * JJ + col];
        *(uint4*)&sT[lo] = *(const uint4*)&Tt[qbase + (size_t)row * JJ + col];
    }
    __syncthreads();
    const int lane = tid & 63, wv = tid >> 6;
    const int wm = wv >> 1, wn = wv & 1;
    const int lr = lane & 15, lg = lane >> 4;
    f32x4 zero4 = {0.f, 0.f, 0.f, 0.f};
    f32x4 accA[2][2], accB[2][2];
    #pragma unroll
    for (int mr = 0; mr < 2; mr++)
        #pragma unroll
        for (int nr = 0; nr < 2; nr++) { accA[mr][nr] = zero4; accB[mr][nr] = zero4; }

    #pragma unroll
    for (int ks = 0; ks < 4; ks++) {
        int kc = ks * 32 + lg * 8;
        s16x8 a0 = *(const s16x8*)&sX[(wm * 32 + lr) * 136 + kc];
        s16x8 a1 = *(const s16x8*)&sX[(wm * 32 + 16 + lr) * 136 + kc];
        s16x8 q0 = *(const s16x8*)&sQ[(wn * 32 + lr) * 136 + kc];
        s16x8 q1 = *(const s16x8*)&sQ[(wn * 32 + 16 + lr) * 136 + kc];
        s16x8 u0 = *(const s16x8*)&sT[(wn * 32 + lr) * 136 + kc];
        s16x8 u1 = *(const s16x8*)&sT[(wn * 32 + 16 + lr) * 136 + kc];
        accA[0][0] = MFMA_BF16(a0, q0, accA[0][0]);
        accA[0][1] = MFMA_BF16(a0, q1, accA[0][1]);
        accA[1][0] = MFMA_BF16(a1, q0, accA[1][0]);
        accA[1][1] = MFMA_BF16(a1, q1, accA[1][1]);
        accB[0][0] = MFMA_BF16(a0, u0, accB[0][0]);
        accB[0][1] = MFMA_BF16(a0, u1, accB[0][1]);
        accB[1][0] = MFMA_BF16(a1, u0, accB[1][0]);
        accB[1][1] = MFMA_BF16(a1, u1, accB[1][1]);
    }

    #pragma unroll
    for (int mr = 0; mr < 2; mr++) {
        #pragma unroll
        for (int reg = 0; reg < 4; reg++) {
            int t = t0 + wm * 32 + mr * 16 + lg * 4 + reg;
            float r = rowrcp[(size_t)b * TT + t];
            const float* Cp = C + ((size_t)b * TT + t) * DD;
            float* op = out + ((size_t)b * TT + t) * (4 * DD);
            #pragma unroll
            for (int nr = 0; nr < 2; nr++) {
                int d = d0 + wn * 32 + nr * 16 + lr;
                float cv = Cp[d];
                float av = accA[mr][nr][reg] * r;
                float bv = accB[mr][nr][reg] * r;
                op[d]          = cv;
                op[DD + d]     = av;
                op[2 * DD + d] = cv * av;
                op[3 * DD + d] = cv * bv;
            }
        }
    }
}

// ---------------------------------------------------------------------------
extern "C" void kernel_launch(void* const* d_in, const int* in_sizes, int n_in,
                              void* d_out, int out_size, void* d_ws, size_t ws_size,
                              hipStream_t stream) {
    const float* C = (const float*)d_in[0];
    const float* Q = (const float*)d_in[1];
    const float* w = (const float*)d_in[2];
    float* out = (float*)d_out;
    float* p = (float*)d_ws;

    u16* Xg  = (u16*)p;     p += (size_t)BB * TT * JJ / 2;   // 8.4 MB
    u16* Qt  = (u16*)p;     p += (size_t)BB * DD * JJ / 2;
    u16* Qhi = (u16*)p;     p += (size_t)BB * JJ * DD / 2;
    u16* Qlo = (u16*)p;     p += (size_t)BB * JJ * DD / 2;
    u16* Tt  = (u16*)p;     p += (size_t)BB * DD * JJ / 2;
    float* qu     = p;      p += BB * JJ;
    float* rowmax = p;      p += BB * TT;
    float* rowrcp = p;      p += BB * TT;
    float* pm     = p;      p += BB * 16;
    float* ps     = p;      p += (size_t)BB * 16 * JJ;

    k_qprep <<<dim3(BB * 2), dim3(256), 0, stream>>>(Q, w, qu, Qhi, Qlo, Qt);
    k_S     <<<dim3(16 * BB), dim3(256), 0, stream>>>(C, Qhi, Qlo, w, qu, Xg, rowmax, rowrcp, pm, ps);
    k_tmp   <<<dim3(8 * BB), dim3(256), 0, stream>>>(Xg, C, rowmax, pm, ps, Tt);
    k_out   <<<dim3(64 * BB), dim3(256), 0, stream>>>(Xg, Qt, Tt, C, rowrcp, out);
}

// Round 8
// 87.993 us; speedup vs baseline: 1.5702x; 1.3146x over previous
//
#include <hip/hip_runtime.h>
#include <math.h>

#define BB 32
#define TT 1024
#define JJ 128
#define DD 256

typedef unsigned short u16;
typedef short s16x8 __attribute__((ext_vector_type(8)));
typedef float f32x4 __attribute__((ext_vector_type(4)));

#define MFMA_BF16(a, b, c) __builtin_amdgcn_mfma_f32_16x16x32_bf16((a), (b), (c), 0, 0, 0)

__device__ inline u16 f2bf(float f) {
    unsigned int u = __float_as_uint(f);
    u += 0x7FFFu + ((u >> 16) & 1u);
    return (u16)(u >> 16);
}
__device__ inline float bf2f(u16 h) {
    return __uint_as_float(((unsigned int)h) << 16);
}

// ---------------------------------------------------------------------------
// K0: per half-batch (64 j rows): qu[j] = Q[j,:]·w_u ; Qhi/Qlo[j,d] split
// bf16 ; Qt[d,j] bf16 transposed. One Q read serves all.
// ---------------------------------------------------------------------------
__global__ __launch_bounds__(256) void k_qprep(const float* __restrict__ Q,
                                               const float* __restrict__ w,
                                               float* __restrict__ qu,
                                               u16* __restrict__ Qhi,
                                               u16* __restrict__ Qlo,
                                               u16* __restrict__ Qt) {
    const int b = blockIdx.x >> 1, jh = blockIdx.x & 1;
    const int tid = threadIdx.x;
    __shared__ float sW[256];
    __shared__ __align__(16) u16 sTr[256 * 72];   // [d][j-local] stride 72
    sW[tid] = w[DD + tid];
    __syncthreads();
    const int jj = tid >> 2, s = tid & 3;         // 64 j x 4 d-segs
    const int j = jh * 64 + jj;
    const float* qp = Q + ((size_t)b * JJ + j) * DD + s * 64;
    u16* hp = Qhi + ((size_t)b * JJ + j) * DD + s * 64;
    u16* lp = Qlo + ((size_t)b * JJ + j) * DD + s * 64;
    float dot = 0.f;
    #pragma unroll
    for (int q = 0; q < 16; q++) {
        float4 v = *(const float4*)(qp + q * 4);
        const float* wq = &sW[s * 64 + q * 4];
        dot += v.x * wq[0] + v.y * wq[1] + v.z * wq[2] + v.w * wq[3];
        ushort4 h, l;
        h.x = f2bf(v.x); l.x = f2bf(v.x - bf2f(h.x));
        h.y = f2bf(v.y); l.y = f2bf(v.y - bf2f(h.y));
        h.z = f2bf(v.z); l.z = f2bf(v.z - bf2f(h.z));
        h.w = f2bf(v.w); l.w = f2bf(v.w - bf2f(h.w));
        *(ushort4*)(hp + q * 4) = h;
        *(ushort4*)(lp + q * 4) = l;
        int d = s * 64 + q * 4;
        sTr[(d + 0) * 72 + jj] = h.x;
        sTr[(d + 1) * 72 + jj] = h.y;
        sTr[(d + 2) * 72 + jj] = h.z;
        sTr[(d + 3) * 72 + jj] = h.w;
    }
    dot += __shfl_xor(dot, 1, 64);
    dot += __shfl_xor(dot, 2, 64);
    if (s == 0) qu[b * JJ + j] = dot;
    __syncthreads();
    const u16* srow = &sTr[tid * 72];
    u16* drow = &Qt[((size_t)b * DD + tid) * JJ + jh * 64];
    #pragma unroll
    for (int q = 0; q < 8; q++) *(uint4*)&drow[q * 8] = *(const uint4*)&srow[q * 8];
}

// ---------------------------------------------------------------------------
// K2 (split-bf16 MFMA): S = ch + qu + (C*w_hu)·Q^T via hi/lo decomposition.
// ch computed inline. Also emits Cbf[t][d] (bf16 C, reused by k_tmp/k_out)
// and Xt[j][t] (bf16 X transposed, for k_tmp's contiguous staging).
// Epilogue: row stats with in-place exp, X bf16, exp-free column partials.
// ---------------------------------------------------------------------------
__global__ __launch_bounds__(256) void k_S(const float* __restrict__ C,
                                           const u16* __restrict__ Qhi,
                                           const u16* __restrict__ Qlo,
                                           const float* __restrict__ w,
                                           const float* __restrict__ qu,
                                           u16* __restrict__ Xg,
                                           u16* __restrict__ Xt,
                                           u16* __restrict__ Cbf,
                                           float* __restrict__ rowmax,
                                           float* __restrict__ rowrcp,
                                           float* __restrict__ pm,
                                           float* __restrict__ ps) {
    const int id = blockIdx.x;
    const int b  = id & 31;
    const int bx = id >> 5;
    const int t0 = bx * 64;
    const int tid = threadIdx.x;

    union SMem {
        struct { u16 Ah[64 * 72]; u16 Al[64 * 72]; u16 Bh[128 * 72]; u16 Bl[128 * 72]; } g;
        struct { float S[64 * 132]; float RM[64]; float W[4]; float ER[64]; float PS2[256]; } e;
    };
    __shared__ __align__(16) SMem sm;
    __shared__ float sCH[64];
    __shared__ float sQU[128];

    if (tid < 128) sQU[tid] = qu[b * JJ + tid];

    const float* whu = w + 2 * DD;
    const float* Cb  = C + ((size_t)b * TT + t0) * DD;

    const int lane = tid & 63, wv = tid >> 6;
    const int wm = wv >> 1, wn = wv & 1;
    const int lr = lane & 15, lg = lane >> 4;

    f32x4 zero4 = {0.f, 0.f, 0.f, 0.f};
    f32x4 acc[2][4];
    #pragma unroll
    for (int m = 0; m < 2; m++)
        #pragma unroll
        for (int n = 0; n < 4; n++) acc[m][n] = zero4;

    const int tA = tid >> 2, sA = (tid & 3) * 16;
    const int jB = tid >> 1, sB = (tid & 1) * 32;
    float chdot = 0.f;

    for (int kc = 0; kc < DD; kc += 64) {
        __syncthreads();
        {   // stage A: (C*w_hu)[64t][64k] -> hi/lo bf16; ch dot; Cbf write
            const float* cp  = Cb + (size_t)tA * DD + kc + sA;
            const float* wp  = whu + kc + sA;
            const float* whp = w + kc + sA;
            float cc[16], ww[16], wh[16];
            #pragma unroll
            for (int q = 0; q < 4; q++) {
                *(float4*)&cc[q * 4] = *(const float4*)(cp + q * 4);
                *(float4*)&ww[q * 4] = *(const float4*)(wp + q * 4);
                *(float4*)&wh[q * 4] = *(const float4*)(whp + q * 4);
            }
            u16 hi16[16], lo16[16], cb16[16];
            #pragma unroll
            for (int u = 0; u < 16; u++) {
                chdot += cc[u] * wh[u];
                cb16[u] = f2bf(cc[u]);
                float v = cc[u] * ww[u];
                u16 h = f2bf(v);
                hi16[u] = h;
                lo16[u] = f2bf(v - bf2f(h));
            }
            u16* cbp = &Cbf[((size_t)b * TT + t0 + tA) * DD + kc + sA];
            *(uint4*)&cbp[0] = *(uint4*)&cb16[0];
            *(uint4*)&cbp[8] = *(uint4*)&cb16[8];
            int o = tA * 72 + sA;
            *(uint4*)&sm.g.Ah[o]     = *(uint4*)&hi16[0];
            *(uint4*)&sm.g.Ah[o + 8] = *(uint4*)&hi16[8];
            *(uint4*)&sm.g.Al[o]     = *(uint4*)&lo16[0];
            *(uint4*)&sm.g.Al[o + 8] = *(uint4*)&lo16[8];
        }
        {   // stage B: Qhi/Qlo[128j][64k] (pure copies)
            const uint4* qh = (const uint4*)&Qhi[((size_t)b * JJ + jB) * DD + kc + sB];
            const uint4* ql = (const uint4*)&Qlo[((size_t)b * JJ + jB) * DD + kc + sB];
            uint4* dh = (uint4*)&sm.g.Bh[jB * 72 + sB];
            uint4* dl = (uint4*)&sm.g.Bl[jB * 72 + sB];
            #pragma unroll
            for (int q = 0; q < 4; q++) { dh[q] = qh[q]; dl[q] = ql[q]; }
        }
        __syncthreads();
        #pragma unroll
        for (int ks = 0; ks < 2; ks++) {
            const int ko = ks * 32 + lg * 8;
            s16x8 ah[2], al[2], bh[4], bl[4];
            #pragma unroll
            for (int m = 0; m < 2; m++) {
                ah[m] = *(const s16x8*)&sm.g.Ah[(wm * 32 + m * 16 + lr) * 72 + ko];
                al[m] = *(const s16x8*)&sm.g.Al[(wm * 32 + m * 16 + lr) * 72 + ko];
            }
            #pragma unroll
            for (int n = 0; n < 4; n++) {
                bh[n] = *(const s16x8*)&sm.g.Bh[(wn * 64 + n * 16 + lr) * 72 + ko];
                bl[n] = *(const s16x8*)&sm.g.Bl[(wn * 64 + n * 16 + lr) * 72 + ko];
            }
            #pragma unroll
            for (int m = 0; m < 2; m++)
                #pragma unroll
                for (int n = 0; n < 4; n++) {
                    f32x4 t = acc[m][n];
                    t = MFMA_BF16(ah[m], bh[n], t);
                    t = MFMA_BF16(ah[m], bl[n], t);
                    t = MFMA_BF16(al[m], bh[n], t);
                    acc[m][n] = t;
                }
        }
    }

    // finalize ch: combine 4 d-segment partials per t-row
    chdot += __shfl_xor(chdot, 1, 64);
    chdot += __shfl_xor(chdot, 2, 64);
    if ((tid & 3) == 0) sCH[tid >> 2] = chdot;

    // ---- epilogue ----
    __syncthreads();
    #pragma unroll
    for (int m = 0; m < 2; m++) {
        int row0 = wm * 32 + m * 16 + lg * 4;
        #pragma unroll
        for (int n = 0; n < 4; n++) {
            int col = wn * 64 + n * 16 + lr;
            float qv = sQU[col];
            #pragma unroll
            for (int reg = 0; reg < 4; reg++)
                sm.e.S[(row0 + reg) * 132 + col] = acc[m][n][reg] + sCH[row0 + reg] + qv;
        }
    }
    __syncthreads();
    {   // pass 1: row stats + in-place exp (S -> X fp32)
        int r = tid >> 2, s = tid & 3;
        float v[32];
        float* Sr = &sm.e.S[r * 132 + s * 32];
        #pragma unroll
        for (int q = 0; q < 8; q++) *(float4*)&v[q * 4] = *(const float4*)&Sr[q * 4];
        float mx = v[0];
        #pragma unroll
        for (int u = 1; u < 32; u++) mx = fmaxf(mx, v[u]);
        mx = fmaxf(mx, __shfl_xor(mx, 1, 64));
        mx = fmaxf(mx, __shfl_xor(mx, 2, 64));
        float sum = 0.f;
        #pragma unroll
        for (int u = 0; u < 32; u++) { v[u] = __expf(v[u] - mx); sum += v[u]; }
        sum += __shfl_xor(sum, 1, 64);
        sum += __shfl_xor(sum, 2, 64);
        #pragma unroll
        for (int q = 0; q < 8; q++) *(float4*)&Sr[q * 4] = *(const float4*)&v[q * 4];
        if (s == 0) {
            sm.e.RM[r] = mx;
            rowmax[(size_t)b * TT + t0 + r] = mx;
            rowrcp[(size_t)b * TT + t0 + r] = 1.0f / sum;
        }
        float wmx = mx;
        wmx = fmaxf(wmx, __shfl_xor(wmx, 4, 64));
        wmx = fmaxf(wmx, __shfl_xor(wmx, 8, 64));
        wmx = fmaxf(wmx, __shfl_xor(wmx, 16, 64));
        wmx = fmaxf(wmx, __shfl_xor(wmx, 32, 64));
        if (lane == 0) sm.e.W[wv] = wmx;
    }
    __syncthreads();
    const float Mb = fmaxf(fmaxf(sm.e.W[0], sm.e.W[1]), fmaxf(sm.e.W[2], sm.e.W[3]));
    if (tid < 64) sm.e.ER[tid] = __expf(sm.e.RM[tid] - Mb);
    // X write [t][j] (no exp)
    #pragma unroll
    for (int i = 0; i < 4; i++) {
        int c = tid + 256 * i;
        int row = c >> 4, j0 = (c & 15) * 8;
        float vv[8];
        *(float4*)&vv[0] = *(const float4*)&sm.e.S[row * 132 + j0];
        *(float4*)&vv[4] = *(const float4*)&sm.e.S[row * 132 + j0 + 4];
        u16 xp[8];
        #pragma unroll
        for (int u = 0; u < 8; u++) xp[u] = f2bf(vv[u]);
        *(uint4*)&Xg[((size_t)b * TT + t0 + row) * JJ + j0] = *(uint4*)&xp[0];
    }
    // Xt write [j][t]: thread = (j, 32-t seg)
    {
        int j = tid & 127, seg = tid >> 7;
        u16 xb[32];
        #pragma unroll
        for (int k = 0; k < 32; k++)
            xb[k] = f2bf(sm.e.S[(seg * 32 + k) * 132 + j]);
        u16* xtp = &Xt[((size_t)b * JJ + j) * TT + t0 + seg * 32];
        #pragma unroll
        for (int q = 0; q < 4; q++) *(uint4*)&xtp[q * 8] = *(uint4*)&xb[q * 8];
    }
    __syncthreads();
    {   // column partials: pure fma against ER (no exp)
        int j = tid & 127, h = tid >> 7;
        float cs = 0.f;
        #pragma unroll
        for (int k = 0; k < 32; k++)
            cs = fmaf(sm.e.S[(h * 32 + k) * 132 + j], sm.e.ER[h * 32 + k], cs);
        sm.e.PS2[h * 128 + j] = cs;
    }
    __syncthreads();
    if (tid < 128) ps[((size_t)b * 16 + bx) * JJ + tid] = sm.e.PS2[tid] + sm.e.PS2[128 + tid];
    if (tid == 0)  pm[b * 16 + bx] = Mb;
}

// ---------------------------------------------------------------------------
// K4 (MFMA): Tt[b,d,j] = sum_t G[t,j]*C[t,d], G = X*er[t]*ec[j].
// Prologue computes K, er, ec per block. Staging now fully vectorized:
// G from Xt [j][t] (contiguous uint4), C^T from Cbf (bf16, no converts).
// id = dh*32 + b -> id%8 = b%8 (XCD owns batch).
// ---------------------------------------------------------------------------
__global__ __launch_bounds__(256) void k_tmp(const u16* __restrict__ Xt,
                                             const u16* __restrict__ Cbf,
                                             const float* __restrict__ rowmax,
                                             const float* __restrict__ pm,
                                             const float* __restrict__ ps,
                                             u16* __restrict__ Tt) {
    const int id = blockIdx.x;
    const int b = id & 31, dh = id >> 5;          // dh in 0..7
    const int d0 = dh * 32;
    const int tid = threadIdx.x;
    __shared__ __align__(16) u16 sG[128 * 72];    // [j][t] stride 72
    __shared__ __align__(16) u16 sCt[32 * 72];    // [d][t] stride 72
    __shared__ float sER[1024];
    __shared__ float sEC[128];
    __shared__ float sPE[16];
    __shared__ float sW2[4];
    const int lane = tid & 63, wv = tid >> 6;

    {   // K_b = max rowmax over batch; er, ec
        float4 rm4 = *(const float4*)&rowmax[(size_t)b * TT + tid * 4];
        float km = fmaxf(fmaxf(rm4.x, rm4.y), fmaxf(rm4.z, rm4.w));
        #pragma unroll
        for (int off = 1; off < 64; off <<= 1) km = fmaxf(km, __shfl_xor(km, off, 64));
        if (lane == 0) sW2[wv] = km;
        __syncthreads();
        const float K = fmaxf(fmaxf(sW2[0], sW2[1]), fmaxf(sW2[2], sW2[3]));
        float4 e4;
        e4.x = __expf(rm4.x - K);
        e4.y = __expf(rm4.y - K);
        e4.z = __expf(rm4.z - K);
        e4.w = __expf(rm4.w - K);
        *(float4*)&sER[tid * 4] = e4;
        if (tid < 16) sPE[tid] = __expf(pm[b * 16 + tid] - K);
        __syncthreads();
        if (tid < 128) {
            float cy = 0.f;
            #pragma unroll
            for (int blk = 0; blk < 16; blk++)
                cy = fmaf(ps[((size_t)b * 16 + blk) * JJ + tid], sPE[blk], cy);
            sEC[tid] = 1.0f / cy;
        }
    }

    const int lr = lane & 15, lg = lane >> 4;
    f32x4 zero4 = {0.f, 0.f, 0.f, 0.f};
    f32x4 acc[2][2];
    acc[0][0] = zero4; acc[0][1] = zero4; acc[1][0] = zero4; acc[1][1] = zero4;

    const int gj = tid >> 1, gs = (tid & 1) * 32;     // G: j row, 32-t seg
    const int ct = tid & 63, cg = (tid >> 6) * 8;     // Ct: t row, 8-d seg

    for (int tt = 0; tt < TT; tt += 64) {
        __syncthreads();
        // stage G^T = Xt * er * ec (contiguous reads + stores)
        {
            float ecj = sEC[gj];
            const u16* xtp = &Xt[((size_t)b * JJ + gj) * TT + tt + gs];
            u16 gb[32];
            #pragma unroll
            for (int q = 0; q < 4; q++) {
                uint4 xv = *(const uint4*)&xtp[q * 8];
                const u16* xp = (const u16*)&xv;
                #pragma unroll
                for (int u = 0; u < 8; u++)
                    gb[q * 8 + u] = f2bf(bf2f(xp[u]) * sER[tt + gs + q * 8 + u] * ecj);
            }
            u16* gp = &sG[gj * 72 + gs];
            #pragma unroll
            for (int q = 0; q < 4; q++) *(uint4*)&gp[q * 8] = *(uint4*)&gb[q * 8];
        }
        // stage C^T from Cbf (8 d of one t-row -> scatter, no converts)
        {
            uint4 cv = *(const uint4*)&Cbf[((size_t)b * TT + tt + ct) * DD + d0 + cg];
            const u16* cp = (const u16*)&cv;
            #pragma unroll
            for (int u = 0; u < 8; u++) sCt[(cg + u) * 72 + ct] = cp[u];
        }
        __syncthreads();
        #pragma unroll
        for (int ks = 0; ks < 2; ks++) {
            int ko = ks * 32 + lg * 8;
            s16x8 a0 = *(const s16x8*)&sG[(wv * 32 + lr) * 72 + ko];
            s16x8 a1 = *(const s16x8*)&sG[(wv * 32 + 16 + lr) * 72 + ko];
            s16x8 b0 = *(const s16x8*)&sCt[(lr) * 72 + ko];
            s16x8 b1 = *(const s16x8*)&sCt[(16 + lr) * 72 + ko];
            acc[0][0] = MFMA_BF16(a0, b0, acc[0][0]);
            acc[0][1] = MFMA_BF16(a0, b1, acc[0][1]);
            acc[1][0] = MFMA_BF16(a1, b0, acc[1][0]);
            acc[1][1] = MFMA_BF16(a1, b1, acc[1][1]);
        }
    }
    #pragma unroll
    for (int mr = 0; mr < 2; mr++)
        #pragma unroll
        for (int nr = 0; nr < 2; nr++)
            #pragma unroll
            for (int reg = 0; reg < 4; reg++) {
                int j = wv * 32 + mr * 16 + lg * 4 + reg;
                int d = d0 + nr * 16 + lr;
                Tt[((size_t)b * DD + d) * JJ + j] = f2bf(acc[mr][nr][reg]);
            }
}

// ---------------------------------------------------------------------------
// K5 (MFMA): A = (X·rowrcp)·Q, Bm = (X·rowrcp)·tmp; out = [C, A, C*A, C*Bm].
// C values from Cbf (bf16). id = k*32 + b -> id%8 = b%8.
// ---------------------------------------------------------------------------
__global__ __launch_bounds__(256) void k_out(const u16* __restrict__ Xg,
                                             const u16* __restrict__ Qt,
                                             const u16* __restrict__ Tt,
                                             const u16* __restrict__ Cbf,
                                             const float* __restrict__ rowrcp,
                                             float* __restrict__ out) {
    const int id = blockIdx.x;
    const int b = id & 31, k = id >> 5;
    const int dc = k & 3, tc = k >> 2;
    const int t0 = tc * 64, d0 = dc * 64;
    const int tid = threadIdx.x;
    __shared__ __align__(16) u16 sX[64 * 136];
    __shared__ __align__(16) u16 sQ[64 * 136];
    __shared__ __align__(16) u16 sT[64 * 136];
    const size_t xbase = ((size_t)b * TT + t0) * JJ;
    const size_t qbase = ((size_t)b * DD + d0) * JJ;
    #pragma unroll
    for (int i = 0; i < 4; i++) {
        int c = tid + 256 * i;
        int row = c >> 4, col = (c & 15) * 8;
        int lo = row * 136 + col;
        *(uint4*)&sX[lo] = *(const uint4*)&Xg[xbase + (size_t)row * JJ + col];
        *(uint4*)&sQ[lo] = *(const uint4*)&Qt[qbase + (size_t)row * JJ + col];
        *(uint4*)&sT[lo] = *(const uint4*)&Tt[qbase + (size_t)row * JJ + col];
    }
    __syncthreads();
    const int lane = tid & 63, wv = tid >> 6;
    const int wm = wv >> 1, wn = wv & 1;
    const int lr = lane & 15, lg = lane >> 4;
    f32x4 zero4 = {0.f, 0.f, 0.f, 0.f};
    f32x4 accA[2][2], accB[2][2];
    #pragma unroll
    for (int mr = 0; mr < 2; mr++)
        #pragma unroll
        for (int nr = 0; nr < 2; nr++) { accA[mr][nr] = zero4; accB[mr][nr] = zero4; }

    #pragma unroll
    for (int ks = 0; ks < 4; ks++) {
        int kc = ks * 32 + lg * 8;
        s16x8 a0 = *(const s16x8*)&sX[(wm * 32 + lr) * 136 + kc];
        s16x8 a1 = *(const s16x8*)&sX[(wm * 32 + 16 + lr) * 136 + kc];
        s16x8 q0 = *(const s16x8*)&sQ[(wn * 32 + lr) * 136 + kc];
        s16x8 q1 = *(const s16x8*)&sQ[(wn * 32 + 16 + lr) * 136 + kc];
        s16x8 u0 = *(const s16x8*)&sT[(wn * 32 + lr) * 136 + kc];
        s16x8 u1 = *(const s16x8*)&sT[(wn * 32 + 16 + lr) * 136 + kc];
        accA[0][0] = MFMA_BF16(a0, q0, accA[0][0]);
        accA[0][1] = MFMA_BF16(a0, q1, accA[0][1]);
        accA[1][0] = MFMA_BF16(a1, q0, accA[1][0]);
        accA[1][1] = MFMA_BF16(a1, q1, accA[1][1]);
        accB[0][0] = MFMA_BF16(a0, u0, accB[0][0]);
        accB[0][1] = MFMA_BF16(a0, u1, accB[0][1]);
        accB[1][0] = MFMA_BF16(a1, u0, accB[1][0]);
        accB[1][1] = MFMA_BF16(a1, u1, accB[1][1]);
    }

    #pragma unroll
    for (int mr = 0; mr < 2; mr++) {
        #pragma unroll
        for (int reg = 0; reg < 4; reg++) {
            int t = t0 + wm * 32 + mr * 16 + lg * 4 + reg;
            float r = rowrcp[(size_t)b * TT + t];
            const u16* Cp = Cbf + ((size_t)b * TT + t) * DD;
            float* op = out + ((size_t)b * TT + t) * (4 * DD);
            #pragma unroll
            for (int nr = 0; nr < 2; nr++) {
                int d = d0 + wn * 32 + nr * 16 + lr;
                float cv = bf2f(Cp[d]);
                float av = accA[mr][nr][reg] * r;
                float bv = accB[mr][nr][reg] * r;
                op[d]          = cv;
                op[DD + d]     = av;
                op[2 * DD + d] = cv * av;
                op[3 * DD + d] = cv * bv;
            }
        }
    }
}

// ---------------------------------------------------------------------------
extern "C" void kernel_launch(void* const* d_in, const int* in_sizes, int n_in,
                              void* d_out, int out_size, void* d_ws, size_t ws_size,
                              hipStream_t stream) {
    const float* C = (const float*)d_in[0];
    const float* Q = (const float*)d_in[1];
    const float* w = (const float*)d_in[2];
    float* out = (float*)d_out;
    float* p = (float*)d_ws;

    u16* Xg  = (u16*)p;     p += (size_t)BB * TT * JJ / 2;   // 8.4 MB
    u16* Xt  = (u16*)p;     p += (size_t)BB * JJ * TT / 2;   // 8.4 MB
    u16* Cbf = (u16*)p;     p += (size_t)BB * TT * DD / 2;   // 16.8 MB
    u16* Qt  = (u16*)p;     p += (size_t)BB * DD * JJ / 2;
    u16* Qhi = (u16*)p;     p += (size_t)BB * JJ * DD / 2;
    u16* Qlo = (u16*)p;     p += (size_t)BB * JJ * DD / 2;
    u16* Tt  = (u16*)p;     p += (size_t)BB * DD * JJ / 2;
    float* qu     = p;      p += BB * JJ;
    float* rowmax = p;      p += BB * TT;
    float* rowrcp = p;      p += BB * TT;
    float* pm     = p;      p += BB * 16;
    float* ps     = p;      p += (size_t)BB * 16 * JJ;

    k_qprep <<<dim3(BB * 2), dim3(256), 0, stream>>>(Q, w, qu, Qhi, Qlo, Qt);
    k_S     <<<dim3(16 * BB), dim3(256), 0, stream>>>(C, Qhi, Qlo, w, qu, Xg, Xt, Cbf, rowmax, rowrcp, pm, ps);
    k_tmp   <<<dim3(8 * BB), dim3(256), 0, stream>>>(Xt, Cbf, rowmax, pm, ps, Tt);
    k_out   <<<dim3(64 * BB), dim3(256), 0, stream>>>(Xg, Qt, Tt, Cbf, rowrcp, out);
}

// Round 9
// 84.527 us; speedup vs baseline: 1.6346x; 1.0410x over previous
//
#include <hip/hip_runtime.h>
#include <math.h>

#define BB 32
#define TT 1024
#define JJ 128
#define DD 256

typedef unsigned short u16;
typedef short s16x8 __attribute__((ext_vector_type(8)));
typedef float f32x4 __attribute__((ext_vector_type(4)));

#define MFMA_BF16(a, b, c) __builtin_amdgcn_mfma_f32_16x16x32_bf16((a), (b), (c), 0, 0, 0)

__device__ inline u16 f2bf(float f) {
    unsigned int u = __float_as_uint(f);
    u += 0x7FFFu + ((u >> 16) & 1u);
    return (u16)(u >> 16);
}
__device__ inline float bf2f(u16 h) {
    return __uint_as_float(((unsigned int)h) << 16);
}

// ---------------------------------------------------------------------------
// K0: per half-batch (64 j rows): qu[j] = Q[j,:]·w_u ; Qhi/Qlo[j,d] split
// bf16 ; Qt[d,j] bf16 transposed. One Q read serves all.
// ---------------------------------------------------------------------------
__global__ __launch_bounds__(256) void k_qprep(const float* __restrict__ Q,
                                               const float* __restrict__ w,
                                               float* __restrict__ qu,
                                               u16* __restrict__ Qhi,
                                               u16* __restrict__ Qlo,
                                               u16* __restrict__ Qt) {
    const int b = blockIdx.x >> 1, jh = blockIdx.x & 1;
    const int tid = threadIdx.x;
    __shared__ float sW[256];
    __shared__ __align__(16) u16 sTr[256 * 72];   // [d][j-local] stride 72
    sW[tid] = w[DD + tid];
    __syncthreads();
    const int jj = tid >> 2, s = tid & 3;         // 64 j x 4 d-segs
    const int j = jh * 64 + jj;
    const float* qp = Q + ((size_t)b * JJ + j) * DD + s * 64;
    u16* hp = Qhi + ((size_t)b * JJ + j) * DD + s * 64;
    u16* lp = Qlo + ((size_t)b * JJ + j) * DD + s * 64;
    float dot = 0.f;
    #pragma unroll
    for (int q = 0; q < 16; q++) {
        float4 v = *(const float4*)(qp + q * 4);
        const float* wq = &sW[s * 64 + q * 4];
        dot += v.x * wq[0] + v.y * wq[1] + v.z * wq[2] + v.w * wq[3];
        ushort4 h, l;
        h.x = f2bf(v.x); l.x = f2bf(v.x - bf2f(h.x));
        h.y = f2bf(v.y); l.y = f2bf(v.y - bf2f(h.y));
        h.z = f2bf(v.z); l.z = f2bf(v.z - bf2f(h.z));
        h.w = f2bf(v.w); l.w = f2bf(v.w - bf2f(h.w));
        *(ushort4*)(hp + q * 4) = h;
        *(ushort4*)(lp + q * 4) = l;
        int d = s * 64 + q * 4;
        sTr[(d + 0) * 72 + jj] = h.x;
        sTr[(d + 1) * 72 + jj] = h.y;
        sTr[(d + 2) * 72 + jj] = h.z;
        sTr[(d + 3) * 72 + jj] = h.w;
    }
    dot += __shfl_xor(dot, 1, 64);
    dot += __shfl_xor(dot, 2, 64);
    if (s == 0) qu[b * JJ + j] = dot;
    __syncthreads();
    const u16* srow = &sTr[tid * 72];
    u16* drow = &Qt[((size_t)b * DD + tid) * JJ + jh * 64];
    #pragma unroll
    for (int q = 0; q < 8; q++) *(uint4*)&drow[q * 8] = *(const uint4*)&srow[q * 8];
}

// ---------------------------------------------------------------------------
// K2 (split-bf16 MFMA): S = ch + qu + (C*w_hu)·Q^T via hi/lo decomposition.
// ch computed inline. Also emits Cbf[t][d] and Xt[j][t].
// Epilogue: row stats with in-place exp; Xg written DIRECTLY from the stats
// registers (no extra LDS pass); exp-free column partials.
// ---------------------------------------------------------------------------
__global__ __launch_bounds__(256) void k_S(const float* __restrict__ C,
                                           const u16* __restrict__ Qhi,
                                           const u16* __restrict__ Qlo,
                                           const float* __restrict__ w,
                                           const float* __restrict__ qu,
                                           u16* __restrict__ Xg,
                                           u16* __restrict__ Xt,
                                           u16* __restrict__ Cbf,
                                           float* __restrict__ rowmax,
                                           float* __restrict__ rowrcp,
                                           float* __restrict__ pm,
                                           float* __restrict__ ps) {
    const int id = blockIdx.x;
    const int b  = id & 31;
    const int bx = id >> 5;
    const int t0 = bx * 64;
    const int tid = threadIdx.x;

    union SMem {
        struct { u16 Ah[64 * 72]; u16 Al[64 * 72]; u16 Bh[128 * 72]; u16 Bl[128 * 72]; } g;
        struct { float S[64 * 132]; float RM[64]; float W[4]; float ER[64]; float PS2[256]; } e;
    };
    __shared__ __align__(16) SMem sm;
    __shared__ float sCH[64];
    __shared__ float sQU[128];

    if (tid < 128) sQU[tid] = qu[b * JJ + tid];

    const float* whu = w + 2 * DD;
    const float* Cb  = C + ((size_t)b * TT + t0) * DD;

    const int lane = tid & 63, wv = tid >> 6;
    const int wm = wv >> 1, wn = wv & 1;
    const int lr = lane & 15, lg = lane >> 4;

    f32x4 zero4 = {0.f, 0.f, 0.f, 0.f};
    f32x4 acc[2][4];
    #pragma unroll
    for (int m = 0; m < 2; m++)
        #pragma unroll
        for (int n = 0; n < 4; n++) acc[m][n] = zero4;

    const int tA = tid >> 2, sA = (tid & 3) * 16;
    const int jB = tid >> 1, sB = (tid & 1) * 32;
    float chdot = 0.f;

    for (int kc = 0; kc < DD; kc += 64) {
        __syncthreads();
        {   // stage A: (C*w_hu)[64t][64k] -> hi/lo bf16; ch dot; Cbf write
            const float* cp  = Cb + (size_t)tA * DD + kc + sA;
            const float* wp  = whu + kc + sA;
            const float* whp = w + kc + sA;
            float cc[16], ww[16], wh[16];
            #pragma unroll
            for (int q = 0; q < 4; q++) {
                *(float4*)&cc[q * 4] = *(const float4*)(cp + q * 4);
                *(float4*)&ww[q * 4] = *(const float4*)(wp + q * 4);
                *(float4*)&wh[q * 4] = *(const float4*)(whp + q * 4);
            }
            u16 hi16[16], lo16[16], cb16[16];
            #pragma unroll
            for (int u = 0; u < 16; u++) {
                chdot += cc[u] * wh[u];
                cb16[u] = f2bf(cc[u]);
                float v = cc[u] * ww[u];
                u16 h = f2bf(v);
                hi16[u] = h;
                lo16[u] = f2bf(v - bf2f(h));
            }
            u16* cbp = &Cbf[((size_t)b * TT + t0 + tA) * DD + kc + sA];
            *(uint4*)&cbp[0] = *(uint4*)&cb16[0];
            *(uint4*)&cbp[8] = *(uint4*)&cb16[8];
            int o = tA * 72 + sA;
            *(uint4*)&sm.g.Ah[o]     = *(uint4*)&hi16[0];
            *(uint4*)&sm.g.Ah[o + 8] = *(uint4*)&hi16[8];
            *(uint4*)&sm.g.Al[o]     = *(uint4*)&lo16[0];
            *(uint4*)&sm.g.Al[o + 8] = *(uint4*)&lo16[8];
        }
        {   // stage B: Qhi/Qlo[128j][64k] (pure copies)
            const uint4* qh = (const uint4*)&Qhi[((size_t)b * JJ + jB) * DD + kc + sB];
            const uint4* ql = (const uint4*)&Qlo[((size_t)b * JJ + jB) * DD + kc + sB];
            uint4* dh = (uint4*)&sm.g.Bh[jB * 72 + sB];
            uint4* dl = (uint4*)&sm.g.Bl[jB * 72 + sB];
            #pragma unroll
            for (int q = 0; q < 4; q++) { dh[q] = qh[q]; dl[q] = ql[q]; }
        }
        __syncthreads();
        #pragma unroll
        for (int ks = 0; ks < 2; ks++) {
            const int ko = ks * 32 + lg * 8;
            s16x8 ah[2], al[2], bh[4], bl[4];
            #pragma unroll
            for (int m = 0; m < 2; m++) {
                ah[m] = *(const s16x8*)&sm.g.Ah[(wm * 32 + m * 16 + lr) * 72 + ko];
                al[m] = *(const s16x8*)&sm.g.Al[(wm * 32 + m * 16 + lr) * 72 + ko];
            }
            #pragma unroll
            for (int n = 0; n < 4; n++) {
                bh[n] = *(const s16x8*)&sm.g.Bh[(wn * 64 + n * 16 + lr) * 72 + ko];
                bl[n] = *(const s16x8*)&sm.g.Bl[(wn * 64 + n * 16 + lr) * 72 + ko];
            }
            #pragma unroll
            for (int m = 0; m < 2; m++)
                #pragma unroll
                for (int n = 0; n < 4; n++) {
                    f32x4 t = acc[m][n];
                    t = MFMA_BF16(ah[m], bh[n], t);
                    t = MFMA_BF16(ah[m], bl[n], t);
                    t = MFMA_BF16(al[m], bh[n], t);
                    acc[m][n] = t;
                }
        }
    }

    // finalize ch: combine 4 d-segment partials per t-row
    chdot += __shfl_xor(chdot, 1, 64);
    chdot += __shfl_xor(chdot, 2, 64);
    if ((tid & 3) == 0) sCH[tid >> 2] = chdot;

    // ---- epilogue ----
    __syncthreads();
    #pragma unroll
    for (int m = 0; m < 2; m++) {
        int row0 = wm * 32 + m * 16 + lg * 4;
        #pragma unroll
        for (int n = 0; n < 4; n++) {
            int col = wn * 64 + n * 16 + lr;
            float qv = sQU[col];
            #pragma unroll
            for (int reg = 0; reg < 4; reg++)
                sm.e.S[(row0 + reg) * 132 + col] = acc[m][n][reg] + sCH[row0 + reg] + qv;
        }
    }
    __syncthreads();
    {   // pass 1: row stats + in-place exp (S -> X fp32) + DIRECT Xg write
        int r = tid >> 2, s = tid & 3;
        float v[32];
        float* Sr = &sm.e.S[r * 132 + s * 32];
        #pragma unroll
        for (int q = 0; q < 8; q++) *(float4*)&v[q * 4] = *(const float4*)&Sr[q * 4];
        float mx = v[0];
        #pragma unroll
        for (int u = 1; u < 32; u++) mx = fmaxf(mx, v[u]);
        mx = fmaxf(mx, __shfl_xor(mx, 1, 64));
        mx = fmaxf(mx, __shfl_xor(mx, 2, 64));
        float sum = 0.f;
        #pragma unroll
        for (int u = 0; u < 32; u++) { v[u] = __expf(v[u] - mx); sum += v[u]; }
        sum += __shfl_xor(sum, 1, 64);
        sum += __shfl_xor(sum, 2, 64);
        #pragma unroll
        for (int q = 0; q < 8; q++) *(float4*)&Sr[q * 4] = *(const float4*)&v[q * 4];
        // Xg direct from registers: row r, cols s*32..s*32+31
        u16 xp[32];
        #pragma unroll
        for (int u = 0; u < 32; u++) xp[u] = f2bf(v[u]);
        u16* xgp = &Xg[((size_t)b * TT + t0 + r) * JJ + s * 32];
        #pragma unroll
        for (int q = 0; q < 4; q++) *(uint4*)&xgp[q * 8] = *(uint4*)&xp[q * 8];
        if (s == 0) {
            sm.e.RM[r] = mx;
            rowmax[(size_t)b * TT + t0 + r] = mx;
            rowrcp[(size_t)b * TT + t0 + r] = 1.0f / sum;
        }
        float wmx = mx;
        wmx = fmaxf(wmx, __shfl_xor(wmx, 4, 64));
        wmx = fmaxf(wmx, __shfl_xor(wmx, 8, 64));
        wmx = fmaxf(wmx, __shfl_xor(wmx, 16, 64));
        wmx = fmaxf(wmx, __shfl_xor(wmx, 32, 64));
        if (lane == 0) sm.e.W[wv] = wmx;
    }
    __syncthreads();
    const float Mb = fmaxf(fmaxf(sm.e.W[0], sm.e.W[1]), fmaxf(sm.e.W[2], sm.e.W[3]));
    if (tid < 64) sm.e.ER[tid] = __expf(sm.e.RM[tid] - Mb);
    // Xt write [j][t]: thread = (j, 32-t seg)
    {
        int j = tid & 127, seg = tid >> 7;
        u16 xb[32];
        #pragma unroll
        for (int k = 0; k < 32; k++)
            xb[k] = f2bf(sm.e.S[(seg * 32 + k) * 132 + j]);
        u16* xtp = &Xt[((size_t)b * JJ + j) * TT + t0 + seg * 32];
        #pragma unroll
        for (int q = 0; q < 4; q++) *(uint4*)&xtp[q * 8] = *(uint4*)&xb[q * 8];
    }
    __syncthreads();
    {   // column partials: pure fma against ER (no exp)
        int j = tid & 127, h = tid >> 7;
        float cs = 0.f;
        #pragma unroll
        for (int k = 0; k < 32; k++)
            cs = fmaf(sm.e.S[(h * 32 + k) * 132 + j], sm.e.ER[h * 32 + k], cs);
        sm.e.PS2[h * 128 + j] = cs;
    }
    __syncthreads();
    if (tid < 128) ps[((size_t)b * 16 + bx) * JJ + tid] = sm.e.PS2[tid] + sm.e.PS2[128 + tid];
    if (tid == 0)  pm[b * 16 + bx] = Mb;
}

// ---------------------------------------------------------------------------
// K4 (MFMA): Tt[d,j] = ec[j] * sum_t X[t,j] * (er[t]*C[t,d]).
// er folded into the (small) C'-staging; ec folded into the epilogue;
// G-staging is now a PURE uint4 copy from Xt. id%8 = b%8 (XCD owns batch).
// ---------------------------------------------------------------------------
__global__ __launch_bounds__(256) void k_tmp(const u16* __restrict__ Xt,
                                             const u16* __restrict__ Cbf,
                                             const float* __restrict__ rowmax,
                                             const float* __restrict__ pm,
                                             const float* __restrict__ ps,
                                             u16* __restrict__ Tt) {
    const int id = blockIdx.x;
    const int b = id & 31, dh = id >> 5;          // dh in 0..7
    const int d0 = dh * 32;
    const int tid = threadIdx.x;
    __shared__ __align__(16) u16 sG[128 * 72];    // [j][t] stride 72 (pure X)
    __shared__ __align__(16) u16 sCt[32 * 72];    // [d][t] stride 72 (er*C)
    __shared__ float sER[1024];
    __shared__ float sEC[128];
    __shared__ float sPE[16];
    __shared__ float sW2[4];
    const int lane = tid & 63, wv = tid >> 6;

    {   // K_b = max rowmax over batch; er, ec = 1/colsum(K-ref)
        float4 rm4 = *(const float4*)&rowmax[(size_t)b * TT + tid * 4];
        float km = fmaxf(fmaxf(rm4.x, rm4.y), fmaxf(rm4.z, rm4.w));
        #pragma unroll
        for (int off = 1; off < 64; off <<= 1) km = fmaxf(km, __shfl_xor(km, off, 64));
        if (lane == 0) sW2[wv] = km;
        __syncthreads();
        const float K = fmaxf(fmaxf(sW2[0], sW2[1]), fmaxf(sW2[2], sW2[3]));
        float4 e4;
        e4.x = __expf(rm4.x - K);
        e4.y = __expf(rm4.y - K);
        e4.z = __expf(rm4.z - K);
        e4.w = __expf(rm4.w - K);
        *(float4*)&sER[tid * 4] = e4;
        if (tid < 16) sPE[tid] = __expf(pm[b * 16 + tid] - K);
        __syncthreads();
        if (tid < 128) {
            float cy = 0.f;
            #pragma unroll
            for (int blk = 0; blk < 16; blk++)
                cy = fmaf(ps[((size_t)b * 16 + blk) * JJ + tid], sPE[blk], cy);
            sEC[tid] = 1.0f / cy;
        }
    }

    const int lr = lane & 15, lg = lane >> 4;
    f32x4 zero4 = {0.f, 0.f, 0.f, 0.f};
    f32x4 acc[2][2];
    acc[0][0] = zero4; acc[0][1] = zero4; acc[1][0] = zero4; acc[1][1] = zero4;

    const int gj = tid >> 1, gs = (tid & 1) * 32;     // G: j row, 32-t seg
    const int ct = tid & 63, cg = (tid >> 6) * 8;     // Ct: t row, 8-d seg

    for (int tt = 0; tt < TT; tt += 64) {
        __syncthreads();
        // stage G = X (pure uint4 copies from Xt)
        {
            const u16* xtp = &Xt[((size_t)b * JJ + gj) * TT + tt + gs];
            u16* gp = &sG[gj * 72 + gs];
            #pragma unroll
            for (int q = 0; q < 4; q++) *(uint4*)&gp[q * 8] = *(const uint4*)&xtp[q * 8];
        }
        // stage C' = er[t]*C[t,d] (8 d of one t-row, scale + scatter)
        {
            float e = sER[tt + ct];
            uint4 cv = *(const uint4*)&Cbf[((size_t)b * TT + tt + ct) * DD + d0 + cg];
            const u16* cp = (const u16*)&cv;
            #pragma unroll
            for (int u = 0; u < 8; u++) sCt[(cg + u) * 72 + ct] = f2bf(bf2f(cp[u]) * e);
        }
        __syncthreads();
        #pragma unroll
        for (int ks = 0; ks < 2; ks++) {
            int ko = ks * 32 + lg * 8;
            s16x8 a0 = *(const s16x8*)&sG[(wv * 32 + lr) * 72 + ko];
            s16x8 a1 = *(const s16x8*)&sG[(wv * 32 + 16 + lr) * 72 + ko];
            s16x8 b0 = *(const s16x8*)&sCt[(lr) * 72 + ko];
            s16x8 b1 = *(const s16x8*)&sCt[(16 + lr) * 72 + ko];
            acc[0][0] = MFMA_BF16(a0, b0, acc[0][0]);
            acc[0][1] = MFMA_BF16(a0, b1, acc[0][1]);
            acc[1][0] = MFMA_BF16(a1, b0, acc[1][0]);
            acc[1][1] = MFMA_BF16(a1, b1, acc[1][1]);
        }
    }
    #pragma unroll
    for (int mr = 0; mr < 2; mr++)
        #pragma unroll
        for (int nr = 0; nr < 2; nr++)
            #pragma unroll
            for (int reg = 0; reg < 4; reg++) {
                int j = wv * 32 + mr * 16 + lg * 4 + reg;
                int d = d0 + nr * 16 + lr;
                Tt[((size_t)b * DD + d) * JJ + j] = f2bf(acc[mr][nr][reg] * sEC[j]);
            }
}

// ---------------------------------------------------------------------------
// K5 (MFMA): A = (X·rowrcp)·Q, Bm = (X·rowrcp)·tmp; out = [C, A, C*A, C*Bm].
// C values from Cbf (bf16). id = k*32 + b -> id%8 = b%8.
// ---------------------------------------------------------------------------
__global__ __launch_bounds__(256) void k_out(const u16* __restrict__ Xg,
                                             const u16* __restrict__ Qt,
                                             const u16* __restrict__ Tt,
                                             const u16* __restrict__ Cbf,
                                             const float* __restrict__ rowrcp,
                                             float* __restrict__ out) {
    const int id = blockIdx.x;
    const int b = id & 31, k = id >> 5;
    const int dc = k & 3, tc = k >> 2;
    const int t0 = tc * 64, d0 = dc * 64;
    const int tid = threadIdx.x;
    __shared__ __align__(16) u16 sX[64 * 136];
    __shared__ __align__(16) u16 sQ[64 * 136];
    __shared__ __align__(16) u16 sT[64 * 136];
    const size_t xbase = ((size_t)b * TT + t0) * JJ;
    const size_t qbase = ((size_t)b * DD + d0) * JJ;
    #pragma unroll
    for (int i = 0; i < 4; i++) {
        int c = tid + 256 * i;
        int row = c >> 4, col = (c & 15) * 8;
        int lo = row * 136 + col;
        *(uint4*)&sX[lo] = *(const uint4*)&Xg[xbase + (size_t)row * JJ + col];
        *(uint4*)&sQ[lo] = *(const uint4*)&Qt[qbase + (size_t)row * JJ + col];
        *(uint4*)&sT[lo] = *(const uint4*)&Tt[qbase + (size_t)row * JJ + col];
    }
    __syncthreads();
    const int lane = tid & 63, wv = tid >> 6;
    const int wm = wv >> 1, wn = wv & 1;
    const int lr = lane & 15, lg = lane >> 4;
    f32x4 zero4 = {0.f, 0.f, 0.f, 0.f};
    f32x4 accA[2][2], accB[2][2];
    #pragma unroll
    for (int mr = 0; mr < 2; mr++)
        #pragma unroll
        for (int nr = 0; nr < 2; nr++) { accA[mr][nr] = zero4; accB[mr][nr] = zero4; }

    #pragma unroll
    for (int ks = 0; ks < 4; ks++) {
        int kc = ks * 32 + lg * 8;
        s16x8 a0 = *(const s16x8*)&sX[(wm * 32 + lr) * 136 + kc];
        s16x8 a1 = *(const s16x8*)&sX[(wm * 32 + 16 + lr) * 136 + kc];
        s16x8 q0 = *(const s16x8*)&sQ[(wn * 32 + lr) * 136 + kc];
        s16x8 q1 = *(const s16x8*)&sQ[(wn * 32 + 16 + lr) * 136 + kc];
        s16x8 u0 = *(const s16x8*)&sT[(wn * 32 + lr) * 136 + kc];
        s16x8 u1 = *(const s16x8*)&sT[(wn * 32 + 16 + lr) * 136 + kc];
        accA[0][0] = MFMA_BF16(a0, q0, accA[0][0]);
        accA[0][1] = MFMA_BF16(a0, q1, accA[0][1]);
        accA[1][0] = MFMA_BF16(a1, q0, accA[1][0]);
        accA[1][1] = MFMA_BF16(a1, q1, accA[1][1]);
        accB[0][0] = MFMA_BF16(a0, u0, accB[0][0]);
        accB[0][1] = MFMA_BF16(a0, u1, accB[0][1]);
        accB[1][0] = MFMA_BF16(a1, u0, accB[1][0]);
        accB[1][1] = MFMA_BF16(a1, u1, accB[1][1]);
    }

    #pragma unroll
    for (int mr = 0; mr < 2; mr++) {
        #pragma unroll
        for (int reg = 0; reg < 4; reg++) {
            int t = t0 + wm * 32 + mr * 16 + lg * 4 + reg;
            float r = rowrcp[(size_t)b * TT + t];
            const u16* Cp = Cbf + ((size_t)b * TT + t) * DD;
            float* op = out + ((size_t)b * TT + t) * (4 * DD);
            #pragma unroll
            for (int nr = 0; nr < 2; nr++) {
                int d = d0 + wn * 32 + nr * 16 + lr;
                float cv = bf2f(Cp[d]);
                float av = accA[mr][nr][reg] * r;
                float bv = accB[mr][nr][reg] * r;
                op[d]          = cv;
                op[DD + d]     = av;
                op[2 * DD + d] = cv * av;
                op[3 * DD + d] = cv * bv;
            }
        }
    }
}

// ---------------------------------------------------------------------------
extern "C" void kernel_launch(void* const* d_in, const int* in_sizes, int n_in,
                              void* d_out, int out_size, void* d_ws, size_t ws_size,
                              hipStream_t stream) {
    const float* C = (const float*)d_in[0];
    const float* Q = (const float*)d_in[1];
    const float* w = (const float*)d_in[2];
    float* out = (float*)d_out;
    float* p = (float*)d_ws;

    u16* Xg  = (u16*)p;     p += (size_t)BB * TT * JJ / 2;   // 8.4 MB
    u16* Xt  = (u16*)p;     p += (size_t)BB * JJ * TT / 2;   // 8.4 MB
    u16* Cbf = (u16*)p;     p += (size_t)BB * TT * DD / 2;   // 16.8 MB
    u16* Qt  = (u16*)p;     p += (size_t)BB * DD * JJ / 2;
    u16* Qhi = (u16*)p;     p += (size_t)BB * JJ * DD / 2;
    u16* Qlo = (u16*)p;     p += (size_t)BB * JJ * DD / 2;
    u16* Tt  = (u16*)p;     p += (size_t)BB * DD * JJ / 2;
    float* qu     = p;      p += BB * JJ;
    float* rowmax = p;      p += BB * TT;
    float* rowrcp = p;      p += BB * TT;
    float* pm     = p;      p += BB * 16;
    float* ps     = p;      p += (size_t)BB * 16 * JJ;

    k_qprep <<<dim3(BB * 2), dim3(256), 0, stream>>>(Q, w, qu, Qhi, Qlo, Qt);
    k_S     <<<dim3(16 * BB), dim3(256), 0, stream>>>(C, Qhi, Qlo, w, qu, Xg, Xt, Cbf, rowmax, rowrcp, pm, ps);
    k_tmp   <<<dim3(8 * BB), dim3(256), 0, stream>>>(Xt, Cbf, rowmax, pm, ps, Tt);
    k_out   <<<dim3(64 * BB), dim3(256), 0, stream>>>(Xg, Qt, Tt, Cbf, rowrcp, out);
}

// Round 10
// 82.018 us; speedup vs baseline: 1.6846x; 1.0306x over previous
//
#include <hip/hip_runtime.h>
#include <math.h>

#define BB 32
#define TT 1024
#define JJ 128
#define DD 256

typedef unsigned short u16;
typedef short s16x8 __attribute__((ext_vector_type(8)));
typedef float f32x4 __attribute__((ext_vector_type(4)));

#define MFMA_BF16(a, b, c) __builtin_amdgcn_mfma_f32_16x16x32_bf16((a), (b), (c), 0, 0, 0)

__device__ inline u16 f2bf(float f) {
    unsigned int u = __float_as_uint(f);
    u += 0x7FFFu + ((u >> 16) & 1u);
    return (u16)(u >> 16);
}
__device__ inline float bf2f(u16 h) {
    return __uint_as_float(((unsigned int)h) << 16);
}

// ---------------------------------------------------------------------------
// K2 (split-bf16 MFMA): S = ch + qu + (C*w_hu)·Q^T via hi/lo decomposition.
// Fully self-contained: B staged from fp32 Q with inline hi/lo split; qu dot
// computed inline (block-local); ch inline; Cbf/Xg/Xt emitted; blocks bx<4
// each emit one 64-d slice of Qt via LDS transpose of the staged Bh tile.
// Epilogue: row stats + in-place exp, direct-register Xg, exp-free col partials.
// id = bx*32 + b -> id%8 = b%8 (XCD owns batch).
// ---------------------------------------------------------------------------
__global__ __launch_bounds__(256) void k_S(const float* __restrict__ C,
                                           const float* __restrict__ Q,
                                           const float* __restrict__ w,
                                           u16* __restrict__ Xg,
                                           u16* __restrict__ Xt,
                                           u16* __restrict__ Cbf,
                                           u16* __restrict__ Qt,
                                           float* __restrict__ rowmax,
                                           float* __restrict__ rowrcp,
                                           float* __restrict__ pm,
                                           float* __restrict__ ps) {
    const int id = blockIdx.x;
    const int b  = id & 31;
    const int bx = id >> 5;
    const int t0 = bx * 64;
    const int tid = threadIdx.x;

    union SMem {
        struct { u16 Ah[64 * 72]; u16 Al[64 * 72]; u16 Bh[128 * 72]; u16 Bl[128 * 72]; } g;
        struct { float S[64 * 132]; float RM[64]; float W[4]; float ER[64]; float PS2[256]; } e;
    };
    __shared__ __align__(16) SMem sm;
    __shared__ float sCH[64];
    __shared__ float sQU[128];

    const float* whu = w + 2 * DD;
    const float* Cb  = C + ((size_t)b * TT + t0) * DD;
    const float* Qb  = Q + (size_t)b * JJ * DD;

    const int lane = tid & 63, wv = tid >> 6;
    const int wm = wv >> 1, wn = wv & 1;
    const int lr = lane & 15, lg = lane >> 4;

    f32x4 zero4 = {0.f, 0.f, 0.f, 0.f};
    f32x4 acc[2][4];
    #pragma unroll
    for (int m = 0; m < 2; m++)
        #pragma unroll
        for (int n = 0; n < 4; n++) acc[m][n] = zero4;

    const int tA = tid >> 2, sA = (tid & 3) * 16;
    const int jB = tid >> 1, sB = (tid & 1) * 32;
    float chdot = 0.f;
    float qdot  = 0.f;

    for (int kc = 0; kc < DD; kc += 64) {
        __syncthreads();
        {   // stage A: (C*w_hu)[64t][64k] -> hi/lo bf16; ch dot; Cbf write
            const float* cp  = Cb + (size_t)tA * DD + kc + sA;
            const float* wp  = whu + kc + sA;
            const float* whp = w + kc + sA;
            float cc[16], ww[16], wh[16];
            #pragma unroll
            for (int q = 0; q < 4; q++) {
                *(float4*)&cc[q * 4] = *(const float4*)(cp + q * 4);
                *(float4*)&ww[q * 4] = *(const float4*)(wp + q * 4);
                *(float4*)&wh[q * 4] = *(const float4*)(whp + q * 4);
            }
            u16 hi16[16], lo16[16], cb16[16];
            #pragma unroll
            for (int u = 0; u < 16; u++) {
                chdot += cc[u] * wh[u];
                cb16[u] = f2bf(cc[u]);
                float v = cc[u] * ww[u];
                u16 h = f2bf(v);
                hi16[u] = h;
                lo16[u] = f2bf(v - bf2f(h));
            }
            u16* cbp = &Cbf[((size_t)b * TT + t0 + tA) * DD + kc + sA];
            *(uint4*)&cbp[0] = *(uint4*)&cb16[0];
            *(uint4*)&cbp[8] = *(uint4*)&cb16[8];
            int o = tA * 72 + sA;
            *(uint4*)&sm.g.Ah[o]     = *(uint4*)&hi16[0];
            *(uint4*)&sm.g.Ah[o + 8] = *(uint4*)&hi16[8];
            *(uint4*)&sm.g.Al[o]     = *(uint4*)&lo16[0];
            *(uint4*)&sm.g.Al[o + 8] = *(uint4*)&lo16[8];
        }
        {   // stage B: Q[128j][64k] fp32 -> hi/lo bf16; qu dot inline
            const float* qp  = Qb + (size_t)jB * DD + kc + sB;
            const float* wup = w + DD + kc + sB;
            float qq[32], wu[32];
            #pragma unroll
            for (int q = 0; q < 8; q++) {
                *(float4*)&qq[q * 4] = *(const float4*)(qp + q * 4);
                *(float4*)&wu[q * 4] = *(const float4*)(wup + q * 4);
            }
            u16 h16[32], l16[32];
            #pragma unroll
            for (int u = 0; u < 32; u++) {
                qdot += qq[u] * wu[u];
                u16 h = f2bf(qq[u]);
                h16[u] = h;
                l16[u] = f2bf(qq[u] - bf2f(h));
            }
            uint4* dh = (uint4*)&sm.g.Bh[jB * 72 + sB];
            uint4* dl = (uint4*)&sm.g.Bl[jB * 72 + sB];
            #pragma unroll
            for (int q = 0; q < 4; q++) { dh[q] = *(uint4*)&h16[q * 8]; dl[q] = *(uint4*)&l16[q * 8]; }
        }
        __syncthreads();
        #pragma unroll
        for (int ks = 0; ks < 2; ks++) {
            const int ko = ks * 32 + lg * 8;
            s16x8 ah[2], al[2], bh[4], bl[4];
            #pragma unroll
            for (int m = 0; m < 2; m++) {
                ah[m] = *(const s16x8*)&sm.g.Ah[(wm * 32 + m * 16 + lr) * 72 + ko];
                al[m] = *(const s16x8*)&sm.g.Al[(wm * 32 + m * 16 + lr) * 72 + ko];
            }
            #pragma unroll
            for (int n = 0; n < 4; n++) {
                bh[n] = *(const s16x8*)&sm.g.Bh[(wn * 64 + n * 16 + lr) * 72 + ko];
                bl[n] = *(const s16x8*)&sm.g.Bl[(wn * 64 + n * 16 + lr) * 72 + ko];
            }
            #pragma unroll
            for (int m = 0; m < 2; m++)
                #pragma unroll
                for (int n = 0; n < 4; n++) {
                    f32x4 t = acc[m][n];
                    t = MFMA_BF16(ah[m], bh[n], t);
                    t = MFMA_BF16(ah[m], bl[n], t);
                    t = MFMA_BF16(al[m], bh[n], t);
                    acc[m][n] = t;
                }
        }
        // Qt emission: block bx == kc/64 transposes Bh [128j][64k] -> Qt [d][j]
        if (bx == (kc >> 6)) {
            int dloc = tid >> 2;
            int j0 = (tid & 3) * 32;
            u16 qb[32];
            #pragma unroll
            for (int u = 0; u < 32; u++) qb[u] = sm.g.Bh[(j0 + u) * 72 + dloc];
            u16* qtp = &Qt[((size_t)b * DD + kc + dloc) * JJ + j0];
            #pragma unroll
            for (int q = 0; q < 4; q++) *(uint4*)&qtp[q * 8] = *(uint4*)&qb[q * 8];
        }
    }

    // finalize ch and qu
    chdot += __shfl_xor(chdot, 1, 64);
    chdot += __shfl_xor(chdot, 2, 64);
    if ((tid & 3) == 0) sCH[tid >> 2] = chdot;
    float qd = qdot + __shfl_xor(qdot, 1, 64);
    if ((tid & 1) == 0) sQU[tid >> 1] = qd;

    // ---- epilogue ----
    __syncthreads();
    #pragma unroll
    for (int m = 0; m < 2; m++) {
        int row0 = wm * 32 + m * 16 + lg * 4;
        #pragma unroll
        for (int n = 0; n < 4; n++) {
            int col = wn * 64 + n * 16 + lr;
            float qv = sQU[col];
            #pragma unroll
            for (int reg = 0; reg < 4; reg++)
                sm.e.S[(row0 + reg) * 132 + col] = acc[m][n][reg] + sCH[row0 + reg] + qv;
        }
    }
    __syncthreads();
    {   // pass 1: row stats + in-place exp (S -> X fp32) + DIRECT Xg write
        int r = tid >> 2, s = tid & 3;
        float v[32];
        float* Sr = &sm.e.S[r * 132 + s * 32];
        #pragma unroll
        for (int q = 0; q < 8; q++) *(float4*)&v[q * 4] = *(const float4*)&Sr[q * 4];
        float mx = v[0];
        #pragma unroll
        for (int u = 1; u < 32; u++) mx = fmaxf(mx, v[u]);
        mx = fmaxf(mx, __shfl_xor(mx, 1, 64));
        mx = fmaxf(mx, __shfl_xor(mx, 2, 64));
        float sum = 0.f;
        #pragma unroll
        for (int u = 0; u < 32; u++) { v[u] = __expf(v[u] - mx); sum += v[u]; }
        sum += __shfl_xor(sum, 1, 64);
        sum += __shfl_xor(sum, 2, 64);
        #pragma unroll
        for (int q = 0; q < 8; q++) *(float4*)&Sr[q * 4] = *(const float4*)&v[q * 4];
        u16 xp[32];
        #pragma unroll
        for (int u = 0; u < 32; u++) xp[u] = f2bf(v[u]);
        u16* xgp = &Xg[((size_t)b * TT + t0 + r) * JJ + s * 32];
        #pragma unroll
        for (int q = 0; q < 4; q++) *(uint4*)&xgp[q * 8] = *(uint4*)&xp[q * 8];
        if (s == 0) {
            sm.e.RM[r] = mx;
            rowmax[(size_t)b * TT + t0 + r] = mx;
            rowrcp[(size_t)b * TT + t0 + r] = 1.0f / sum;
        }
        float wmx = mx;
        wmx = fmaxf(wmx, __shfl_xor(wmx, 4, 64));
        wmx = fmaxf(wmx, __shfl_xor(wmx, 8, 64));
        wmx = fmaxf(wmx, __shfl_xor(wmx, 16, 64));
        wmx = fmaxf(wmx, __shfl_xor(wmx, 32, 64));
        if (lane == 0) sm.e.W[wv] = wmx;
    }
    __syncthreads();
    const float Mb = fmaxf(fmaxf(sm.e.W[0], sm.e.W[1]), fmaxf(sm.e.W[2], sm.e.W[3]));
    if (tid < 64) sm.e.ER[tid] = __expf(sm.e.RM[tid] - Mb);
    // Xt write [j][t]: thread = (j, 32-t seg)
    {
        int j = tid & 127, seg = tid >> 7;
        u16 xb[32];
        #pragma unroll
        for (int k = 0; k < 32; k++)
            xb[k] = f2bf(sm.e.S[(seg * 32 + k) * 132 + j]);
        u16* xtp = &Xt[((size_t)b * JJ + j) * TT + t0 + seg * 32];
        #pragma unroll
        for (int q = 0; q < 4; q++) *(uint4*)&xtp[q * 8] = *(uint4*)&xb[q * 8];
    }
    __syncthreads();
    {   // column partials: pure fma against ER (no exp)
        int j = tid & 127, h = tid >> 7;
        float cs = 0.f;
        #pragma unroll
        for (int k = 0; k < 32; k++)
            cs = fmaf(sm.e.S[(h * 32 + k) * 132 + j], sm.e.ER[h * 32 + k], cs);
        sm.e.PS2[h * 128 + j] = cs;
    }
    __syncthreads();
    if (tid < 128) ps[((size_t)b * 16 + bx) * JJ + tid] = sm.e.PS2[tid] + sm.e.PS2[128 + tid];
    if (tid == 0)  pm[b * 16 + bx] = Mb;
}

// ---------------------------------------------------------------------------
// K4 (MFMA): Tt[d,j] = ec[j] * sum_t X[t,j] * (er[t]*C[t,d]).
// er folded into C'-staging; ec into epilogue; G-staging = pure uint4 copies.
// id%8 = b%8 (XCD owns batch).
// ---------------------------------------------------------------------------
__global__ __launch_bounds__(256) void k_tmp(const u16* __restrict__ Xt,
                                             const u16* __restrict__ Cbf,
                                             const float* __restrict__ rowmax,
                                             const float* __restrict__ pm,
                                             const float* __restrict__ ps,
                                             u16* __restrict__ Tt) {
    const int id = blockIdx.x;
    const int b = id & 31, dh = id >> 5;          // dh in 0..7
    const int d0 = dh * 32;
    const int tid = threadIdx.x;
    __shared__ __align__(16) u16 sG[128 * 72];    // [j][t] stride 72 (pure X)
    __shared__ __align__(16) u16 sCt[32 * 72];    // [d][t] stride 72 (er*C)
    __shared__ float sER[1024];
    __shared__ float sEC[128];
    __shared__ float sPE[16];
    __shared__ float sW2[4];
    const int lane = tid & 63, wv = tid >> 6;

    {   // K_b = max rowmax over batch; er, ec = 1/colsum(K-ref)
        float4 rm4 = *(const float4*)&rowmax[(size_t)b * TT + tid * 4];
        float km = fmaxf(fmaxf(rm4.x, rm4.y), fmaxf(rm4.z, rm4.w));
        #pragma unroll
        for (int off = 1; off < 64; off <<= 1) km = fmaxf(km, __shfl_xor(km, off, 64));
        if (lane == 0) sW2[wv] = km;
        __syncthreads();
        const float K = fmaxf(fmaxf(sW2[0], sW2[1]), fmaxf(sW2[2], sW2[3]));
        float4 e4;
        e4.x = __expf(rm4.x - K);
        e4.y = __expf(rm4.y - K);
        e4.z = __expf(rm4.z - K);
        e4.w = __expf(rm4.w - K);
        *(float4*)&sER[tid * 4] = e4;
        if (tid < 16) sPE[tid] = __expf(pm[b * 16 + tid] - K);
        __syncthreads();
        if (tid < 128) {
            float cy = 0.f;
            #pragma unroll
            for (int blk = 0; blk < 16; blk++)
                cy = fmaf(ps[((size_t)b * 16 + blk) * JJ + tid], sPE[blk], cy);
            sEC[tid] = 1.0f / cy;
        }
    }

    const int lr = lane & 15, lg = lane >> 4;
    f32x4 zero4 = {0.f, 0.f, 0.f, 0.f};
    f32x4 acc[2][2];
    acc[0][0] = zero4; acc[0][1] = zero4; acc[1][0] = zero4; acc[1][1] = zero4;

    const int gj = tid >> 1, gs = (tid & 1) * 32;     // G: j row, 32-t seg
    const int ct = tid & 63, cg = (tid >> 6) * 8;     // Ct: t row, 8-d seg

    for (int tt = 0; tt < TT; tt += 64) {
        __syncthreads();
        {   // stage G = X (pure uint4 copies from Xt)
            const u16* xtp = &Xt[((size_t)b * JJ + gj) * TT + tt + gs];
            u16* gp = &sG[gj * 72 + gs];
            #pragma unroll
            for (int q = 0; q < 4; q++) *(uint4*)&gp[q * 8] = *(const uint4*)&xtp[q * 8];
        }
        {   // stage C' = er[t]*C[t,d]
            float e = sER[tt + ct];
            uint4 cv = *(const uint4*)&Cbf[((size_t)b * TT + tt + ct) * DD + d0 + cg];
            const u16* cp = (const u16*)&cv;
            #pragma unroll
            for (int u = 0; u < 8; u++) sCt[(cg + u) * 72 + ct] = f2bf(bf2f(cp[u]) * e);
        }
        __syncthreads();
        #pragma unroll
        for (int ks = 0; ks < 2; ks++) {
            int ko = ks * 32 + lg * 8;
            s16x8 a0 = *(const s16x8*)&sG[(wv * 32 + lr) * 72 + ko];
            s16x8 a1 = *(const s16x8*)&sG[(wv * 32 + 16 + lr) * 72 + ko];
            s16x8 b0 = *(const s16x8*)&sCt[(lr) * 72 + ko];
            s16x8 b1 = *(const s16x8*)&sCt[(16 + lr) * 72 + ko];
            acc[0][0] = MFMA_BF16(a0, b0, acc[0][0]);
            acc[0][1] = MFMA_BF16(a0, b1, acc[0][1]);
            acc[1][0] = MFMA_BF16(a1, b0, acc[1][0]);
            acc[1][1] = MFMA_BF16(a1, b1, acc[1][1]);
        }
    }
    #pragma unroll
    for (int mr = 0; mr < 2; mr++)
        #pragma unroll
        for (int nr = 0; nr < 2; nr++)
            #pragma unroll
            for (int reg = 0; reg < 4; reg++) {
                int j = wv * 32 + mr * 16 + lg * 4 + reg;
                int d = d0 + nr * 16 + lr;
                Tt[((size_t)b * DD + d) * JJ + j] = f2bf(acc[mr][nr][reg] * sEC[j]);
            }
}

// ---------------------------------------------------------------------------
// K5 (MFMA): A = (X·rowrcp)·Q, Bm = (X·rowrcp)·tmp; out = [C, A, C*A, C*Bm].
// C values from Cbf (bf16). id = k*32 + b -> id%8 = b%8.
// ---------------------------------------------------------------------------
__global__ __launch_bounds__(256) void k_out(const u16* __restrict__ Xg,
                                             const u16* __restrict__ Qt,
                                             const u16* __restrict__ Tt,
                                             const u16* __restrict__ Cbf,
                                             const float* __restrict__ rowrcp,
                                             float* __restrict__ out) {
    const int id = blockIdx.x;
    const int b = id & 31, k = id >> 5;
    const int dc = k & 3, tc = k >> 2;
    const int t0 = tc * 64, d0 = dc * 64;
    const int tid = threadIdx.x;
    __shared__ __align__(16) u16 sX[64 * 136];
    __shared__ __align__(16) u16 sQ[64 * 136];
    __shared__ __align__(16) u16 sT[64 * 136];
    const size_t xbase = ((size_t)b * TT + t0) * JJ;
    const size_t qbase = ((size_t)b * DD + d0) * JJ;
    #pragma unroll
    for (int i = 0; i < 4; i++) {
        int c = tid + 256 * i;
        int row = c >> 4, col = (c & 15) * 8;
        int lo = row * 136 + col;
        *(uint4*)&sX[lo] = *(const uint4*)&Xg[xbase + (size_t)row * JJ + col];
        *(uint4*)&sQ[lo] = *(const uint4*)&Qt[qbase + (size_t)row * JJ + col];
        *(uint4*)&sT[lo] = *(const uint4*)&Tt[qbase + (size_t)row * JJ + col];
    }
    __syncthreads();
    const int lane = tid & 63, wv = tid >> 6;
    const int wm = wv >> 1, wn = wv & 1;
    const int lr = lane & 15, lg = lane >> 4;
    f32x4 zero4 = {0.f, 0.f, 0.f, 0.f};
    f32x4 accA[2][2], accB[2][2];
    #pragma unroll
    for (int mr = 0; mr < 2; mr++)
        #pragma unroll
        for (int nr = 0; nr < 2; nr++) { accA[mr][nr] = zero4; accB[mr][nr] = zero4; }

    #pragma unroll
    for (int ks = 0; ks < 4; ks++) {
        int kc = ks * 32 + lg * 8;
        s16x8 a0 = *(const s16x8*)&sX[(wm * 32 + lr) * 136 + kc];
        s16x8 a1 = *(const s16x8*)&sX[(wm * 32 + 16 + lr) * 136 + kc];
        s16x8 q0 = *(const s16x8*)&sQ[(wn * 32 + lr) * 136 + kc];
        s16x8 q1 = *(const s16x8*)&sQ[(wn * 32 + 16 + lr) * 136 + kc];
        s16x8 u0 = *(const s16x8*)&sT[(wn * 32 + lr) * 136 + kc];
        s16x8 u1 = *(const s16x8*)&sT[(wn * 32 + 16 + lr) * 136 + kc];
        accA[0][0] = MFMA_BF16(a0, q0, accA[0][0]);
        accA[0][1] = MFMA_BF16(a0, q1, accA[0][1]);
        accA[1][0] = MFMA_BF16(a1, q0, accA[1][0]);
        accA[1][1] = MFMA_BF16(a1, q1, accA[1][1]);
        accB[0][0] = MFMA_BF16(a0, u0, accB[0][0]);
        accB[0][1] = MFMA_BF16(a0, u1, accB[0][1]);
        accB[1][0] = MFMA_BF16(a1, u0, accB[1][0]);
        accB[1][1] = MFMA_BF16(a1, u1, accB[1][1]);
    }

    #pragma unroll
    for (int mr = 0; mr < 2; mr++) {
        #pragma unroll
        for (int reg = 0; reg < 4; reg++) {
            int t = t0 + wm * 32 + mr * 16 + lg * 4 + reg;
            float r = rowrcp[(size_t)b * TT + t];
            const u16* Cp = Cbf + ((size_t)b * TT + t) * DD;
            float* op = out + ((size_t)b * TT + t) * (4 * DD);
            #pragma unroll
            for (int nr = 0; nr < 2; nr++) {
                int d = d0 + wn * 32 + nr * 16 + lr;
                float cv = bf2f(Cp[d]);
                float av = accA[mr][nr][reg] * r;
                float bv = accB[mr][nr][reg] * r;
                op[d]          = cv;
                op[DD + d]     = av;
                op[2 * DD + d] = cv * av;
                op[3 * DD + d] = cv * bv;
            }
        }
    }
}

// ---------------------------------------------------------------------------
extern "C" void kernel_launch(void* const* d_in, const int* in_sizes, int n_in,
                              void* d_out, int out_size, void* d_ws, size_t ws_size,
                              hipStream_t stream) {
    const float* C = (const float*)d_in[0];
    const float* Q = (const float*)d_in[1];
    const float* w = (const float*)d_in[2];
    float* out = (float*)d_out;
    float* p = (float*)d_ws;

    u16* Xg  = (u16*)p;     p += (size_t)BB * TT * JJ / 2;   // 8.4 MB
    u16* Xt  = (u16*)p;     p += (size_t)BB * JJ * TT / 2;   // 8.4 MB
    u16* Cbf = (u16*)p;     p += (size_t)BB * TT * DD / 2;   // 16.8 MB
    u16* Qt  = (u16*)p;     p += (size_t)BB * DD * JJ / 2;
    u16* Tt  = (u16*)p;     p += (size_t)BB * DD * JJ / 2;
    float* rowmax = p;      p += BB * TT;
    float* rowrcp = p;      p += BB * TT;
    float* pm     = p;      p += BB * 16;
    float* ps     = p;      p += (size_t)BB * 16 * JJ;

    k_S     <<<dim3(16 * BB), dim3(256), 0, stream>>>(C, Q, w, Xg, Xt, Cbf, Qt, rowmax, rowrcp, pm, ps);
    k_tmp   <<<dim3(8 * BB), dim3(256), 0, stream>>>(Xt, Cbf, rowmax, pm, ps, Tt);
    k_out   <<<dim3(64 * BB), dim3(256), 0, stream>>>(Xg, Qt, Tt, Cbf, rowrcp, out);
}